// Round 1
// baseline (1021.076 us; speedup 1.0000x reference)
//
#include <hip/hip_runtime.h>
#include <math.h>

#define B_ROWS 8192
#define DV_DIM 1024
#define DT_DIM 768
#define H_DIM 256
#define C_CLS 5
#define GH_DIM 128
#define K_NN 8
#define FD_DIM 512
#define GI_DIM 773
#define XCOLS 1797
#define NEGV -1000000000.0f
#define LN_EPS_F 1e-5f
#define BN_EPS_F 1e-5f
#define N_IMG 512
#define EW_F 0.01f
#define ALPHA_F 0.5f

// ---------------- extract coords / img, count buckets ----------------
__global__ void zero_cnt_kernel(int* cnt) {
    cnt[threadIdx.x] = 0;
}

__global__ void extract_kernel(const float* __restrict__ x,
                               float* __restrict__ cx, float* __restrict__ cy,
                               float* __restrict__ sq, int* __restrict__ imgi,
                               int* __restrict__ cnt) {
    int i = blockIdx.x * blockDim.x + threadIdx.x;
    if (i >= B_ROWS) return;
    const float* row = x + (size_t)i * XCOLS;
    float a = row[DV_DIM + DT_DIM];
    float b = row[DV_DIM + DT_DIM + 1];
    cx[i] = a; cy[i] = b; sq[i] = a * a + b * b;
    int m = (int)row[DV_DIM + DT_DIM + 4];
    imgi[i] = m;
    atomicAdd(&cnt[m], 1);
}

__global__ void scan_kernel(const int* __restrict__ cnt, int* __restrict__ start,
                            int* __restrict__ cursor) {
    __shared__ int s[N_IMG];
    int t = threadIdx.x;
    s[t] = cnt[t];
    __syncthreads();
    for (int off = 1; off < N_IMG; off <<= 1) {
        int v = (t >= off) ? s[t - off] : 0;
        __syncthreads();
        s[t] += v;
        __syncthreads();
    }
    int st = s[t] - cnt[t];  // exclusive
    start[t] = st;
    cursor[t] = st;
}

__global__ void scatter_kernel(const int* __restrict__ imgi, int* __restrict__ cursor,
                               int* __restrict__ perm) {
    int i = blockIdx.x * blockDim.x + threadIdx.x;
    if (i >= B_ROWS) return;
    int pos = atomicAdd(&cursor[imgi[i]], 1);
    perm[pos] = i;
}

// ---------------- layernorm (row-per-block) ----------------
__global__ __launch_bounds__(256) void ln_kernel(const float* __restrict__ x, int colOff, int D,
                                                 const float* __restrict__ g,
                                                 const float* __restrict__ b,
                                                 float* __restrict__ y) {
    int row = blockIdx.x;
    const float* xr = x + (size_t)row * XCOLS + colOff;
    float* yr = y + (size_t)row * D;
    float vals[4];
    int n = 0;
    float sum = 0.f;
    for (int j = threadIdx.x; j < D; j += 256) { float v = xr[j]; vals[n++] = v; sum += v; }
    __shared__ float red[256];
    red[threadIdx.x] = sum;
    __syncthreads();
    for (int off = 128; off; off >>= 1) {
        if (threadIdx.x < off) red[threadIdx.x] += red[threadIdx.x + off];
        __syncthreads();
    }
    float mean = red[0] / (float)D;
    __syncthreads();
    float vs = 0.f;
    for (int k = 0; k < n; ++k) { float d = vals[k] - mean; vs += d * d; }
    red[threadIdx.x] = vs;
    __syncthreads();
    for (int off = 128; off; off >>= 1) {
        if (threadIdx.x < off) red[threadIdx.x] += red[threadIdx.x + off];
        __syncthreads();
    }
    float var = red[0] / (float)D;
    float rs = rsqrtf(var + LN_EPS_F);
    int k2 = 0;
    for (int j = threadIdx.x; j < D; j += 256) {
        yr[j] = (vals[k2++] - mean) * rs * g[j] + b[j];
    }
}

// ---------------- tiled fp32 GEMM with fused epilogues ----------------
// C[M,N](ldc) = epilogue(A[M,K] @ B[K,N] + bias)
// mode 0: C = acc+bias
// mode 1: C = relu(acc+bias)
// mode 2: C = C + alpha*(acc+bias)
// mode 3: C = relu((acc+bias)*(sg[c]/sqrt(1+eps)) + sb[c])
#define BM 64
#define BN 64
#define BK 16
__global__ __launch_bounds__(256) void sgemm_kernel(
    const float* __restrict__ A, const float* __restrict__ B,
    float* __restrict__ C, const float* __restrict__ bias,
    const float* __restrict__ sg, const float* __restrict__ sb,
    int M, int N, int K, int ldc, int mode, float alpha) {
    __shared__ float As[BK][BM + 1];
    __shared__ float Bs[BK][BN + 1];
    int tid = threadIdx.x;
    int tx = tid % 16, ty = tid / 16;
    int rowBase = blockIdx.y * BM;
    int colBase = blockIdx.x * BN;
    float acc[4][4] = {};
    for (int k0 = 0; k0 < K; k0 += BK) {
#pragma unroll
        for (int l = 0; l < 4; ++l) {
            int idx = tid + l * 256;
            int r = idx / BK, c = idx % BK;
            int kk = k0 + c;
            As[c][r] = (kk < K) ? A[(size_t)(rowBase + r) * K + kk] : 0.f;
        }
#pragma unroll
        for (int l = 0; l < 4; ++l) {
            int idx = tid + l * 256;
            int r = idx / BN, c = idx % BN;
            int kk = k0 + r;
            Bs[r][c] = (kk < K) ? B[(size_t)kk * N + colBase + c] : 0.f;
        }
        __syncthreads();
#pragma unroll
        for (int kk = 0; kk < BK; ++kk) {
            float a[4], b[4];
#pragma unroll
            for (int m = 0; m < 4; ++m) a[m] = As[kk][ty * 4 + m];
#pragma unroll
            for (int n = 0; n < 4; ++n) b[n] = Bs[kk][tx * 4 + n];
#pragma unroll
            for (int m = 0; m < 4; ++m)
#pragma unroll
                for (int n = 0; n < 4; ++n) acc[m][n] = fmaf(a[m], b[n], acc[m][n]);
        }
        __syncthreads();
    }
#pragma unroll
    for (int m = 0; m < 4; ++m) {
#pragma unroll
        for (int n = 0; n < 4; ++n) {
            int r = rowBase + ty * 4 + m;
            int c = colBase + tx * 4 + n;
            float v = acc[m][n] + (bias ? bias[c] : 0.f);
            size_t o = (size_t)r * ldc + c;
            if (mode == 1) {
                v = fmaxf(v, 0.f);
                C[o] = v;
            } else if (mode == 2) {
                C[o] = C[o] + alpha * v;
            } else if (mode == 3) {
                v = v * (sg[c] / sqrtf(1.f + BN_EPS_F)) + sb[c];
                C[o] = fmaxf(v, 0.f);
            } else {
                C[o] = v;
            }
        }
    }
}

// ---------------- small-N row matvec (wave per row) ----------------
// Y[row, 0..NOUT) = X[row,:K] @ W[K,NOUT] + bias ; optional softmax
template <int NOUT, int SOFTMAX>
__global__ __launch_bounds__(256) void rowvec_kernel(const float* __restrict__ X, int ldx, int K,
                                                     const float* __restrict__ W,
                                                     const float* __restrict__ bias,
                                                     float* __restrict__ Y, int ldy) {
    int wave = threadIdx.x >> 6;
    int lane = threadIdx.x & 63;
    int row = blockIdx.x * 4 + wave;
    if (row >= B_ROWS) return;
    const float* xr = X + (size_t)row * ldx;
    float acc[NOUT];
#pragma unroll
    for (int n = 0; n < NOUT; ++n) acc[n] = 0.f;
    for (int k = lane; k < K; k += 64) {
        float xv = xr[k];
#pragma unroll
        for (int n = 0; n < NOUT; ++n) acc[n] = fmaf(xv, W[(size_t)k * NOUT + n], acc[n]);
    }
#pragma unroll
    for (int n = 0; n < NOUT; ++n)
        for (int off = 32; off; off >>= 1) acc[n] += __shfl_down(acc[n], off);
    if (lane == 0) {
#pragma unroll
        for (int n = 0; n < NOUT; ++n) acc[n] += bias[n];
        if (SOFTMAX) {
            float mx = acc[0];
#pragma unroll
            for (int n = 1; n < NOUT; ++n) mx = fmaxf(mx, acc[n]);
            float s = 0.f;
#pragma unroll
            for (int n = 0; n < NOUT; ++n) { acc[n] = expf(acc[n] - mx); s += acc[n]; }
            float inv = 1.f / s;
#pragma unroll
            for (int n = 0; n < NOUT; ++n) acc[n] *= inv;
        }
#pragma unroll
        for (int n = 0; n < NOUT; ++n) Y[(size_t)row * ldy + n] = acc[n];
    }
}

// ---------------- gate head: 128 -> 2, softmax, entropy ----------------
__global__ __launch_bounds__(256) void gate_kernel(const float* __restrict__ gh,
                                                   const float* __restrict__ W2,
                                                   const float* __restrict__ b2,
                                                   float* __restrict__ gp,
                                                   float* __restrict__ ent) {
    int wave = threadIdx.x >> 6;
    int lane = threadIdx.x & 63;
    int row = blockIdx.x * 4 + wave;
    if (row >= B_ROWS) return;
    const float* xr = gh + (size_t)row * GH_DIM;
    float a0 = 0.f, a1 = 0.f;
    for (int k = lane; k < GH_DIM; k += 64) {
        float xv = xr[k];
        a0 = fmaf(xv, W2[k * 2 + 0], a0);
        a1 = fmaf(xv, W2[k * 2 + 1], a1);
    }
    for (int off = 32; off; off >>= 1) {
        a0 += __shfl_down(a0, off);
        a1 += __shfl_down(a1, off);
    }
    if (lane == 0) {
        float l0 = a0 + b2[0], l1 = a1 + b2[1];
        float mx = fmaxf(l0, l1);
        float e0 = expf(l0 - mx), e1 = expf(l1 - mx);
        float s = e0 + e1;
        float p0 = e0 / s, p1 = e1 / s;
        gp[(size_t)row * 2 + 0] = p0;
        gp[(size_t)row * 2 + 1] = p1;
        ent[row] = -(p0 * logf(p0 + 1e-8f) + p1 * logf(p1 + 1e-8f));
    }
}

__global__ void ent_reduce_kernel(const float* __restrict__ ent, float* __restrict__ out) {
    __shared__ float red[256];
    float s = 0.f;
    for (int i = threadIdx.x; i < B_ROWS; i += 256) s += ent[i];
    red[threadIdx.x] = s;
    __syncthreads();
    for (int off = 128; off; off >>= 1) {
        if (threadIdx.x < off) red[threadIdx.x] += red[threadIdx.x + off];
        __syncthreads();
    }
    if (threadIdx.x == 0) out[0] = red[0] * (EW_F / (float)B_ROWS);
}

// ---------------- KNN top-8 select (thread per row) ----------------
__global__ void knn_kernel(const float* __restrict__ cx, const float* __restrict__ cy,
                           const float* __restrict__ sq, const int* __restrict__ imgi,
                           const int* __restrict__ cnt, const int* __restrict__ start,
                           const int* __restrict__ perm, int* __restrict__ knn_idx,
                           float* __restrict__ knn_w) {
    int i = blockIdx.x * blockDim.x + threadIdx.x;
    if (i >= B_ROWS) return;
    float xi = cx[i], yi = cy[i], si = sq[i];
    float vals[K_NN];
    int ids[K_NN];
#pragma unroll
    for (int k = 0; k < K_NN; ++k) { vals[k] = NEGV; ids[k] = i; }
    int m = imgi[i];
    int s = cnt[m];
    if (s >= 2) {
        int st = start[m];
        for (int t = 0; t < s; ++t) {
            int j = perm[st + t];
            if (j == i) continue;
            float d2 = si + sq[j] - 2.f * (xi * cx[j] + yi * cy[j]);
            d2 = fmaxf(d2, 0.f);
            float v = -sqrtf(d2);
            if (v > vals[K_NN - 1]) {
                int p = K_NN - 1;
                while (p > 0 && vals[p - 1] < v) {
                    vals[p] = vals[p - 1];
                    ids[p] = ids[p - 1];
                    --p;
                }
                vals[p] = v;
                ids[p] = j;
            }
        }
    } else {
        // fallback: no same-image neighbor -> all points except self
        for (int j = 0; j < B_ROWS; ++j) {
            if (j == i) continue;
            float d2 = si + sq[j] - 2.f * (xi * cx[j] + yi * cy[j]);
            d2 = fmaxf(d2, 0.f);
            float v = -sqrtf(d2);
            if (v > vals[K_NN - 1]) {
                int p = K_NN - 1;
                while (p > 0 && vals[p - 1] < v) {
                    vals[p] = vals[p - 1];
                    ids[p] = ids[p - 1];
                    --p;
                }
                vals[p] = v;
                ids[p] = j;
            }
        }
    }
    float mx = vals[0];
    float e[K_NN];
    float sum = 0.f;
#pragma unroll
    for (int k = 0; k < K_NN; ++k) { e[k] = expf(vals[k] - mx); sum += e[k]; }
    float inv = 1.f / sum;
#pragma unroll
    for (int k = 0; k < K_NN; ++k) {
        knn_w[(size_t)i * K_NN + k] = e[k] * inv;
        knn_idx[(size_t)i * K_NN + k] = ids[k];
    }
}

// ---------------- weighted gather aggregate ----------------
__global__ __launch_bounds__(256) void agg_kernel(const float* __restrict__ feat,
                                                  const int* __restrict__ knn_idx,
                                                  const float* __restrict__ knn_w,
                                                  float* __restrict__ out) {
    int row = blockIdx.x;
    int jj[K_NN];
    float ww[K_NN];
#pragma unroll
    for (int k = 0; k < K_NN; ++k) {
        jj[k] = knn_idx[(size_t)row * K_NN + k];
        ww[k] = knn_w[(size_t)row * K_NN + k];
    }
    for (int d = threadIdx.x; d < FD_DIM; d += 256) {
        float s = 0.f;
#pragma unroll
        for (int k = 0; k < K_NN; ++k) s = fmaf(ww[k], feat[(size_t)jj[k] * FD_DIM + d], s);
        out[(size_t)row * FD_DIM + d] = s;
    }
}

// ---------------- concat gate_in = [base(512), cp(5), token(256)] ----------------
__global__ void concat_kernel(const float* __restrict__ base, const float* __restrict__ cp,
                              const float* __restrict__ token, float* __restrict__ gi) {
    int r = blockIdx.x;
    float* out = gi + (size_t)r * GI_DIM;
    for (int j = threadIdx.x; j < GI_DIM; j += 256) {
        float v;
        if (j < FD_DIM) v = base[(size_t)r * FD_DIM + j];
        else if (j < FD_DIM + C_CLS) v = cp[(size_t)r * C_CLS + (j - FD_DIM)];
        else v = token[(size_t)r * H_DIM + (j - FD_DIM - C_CLS)];
        out[j] = v;
    }
}

// ---------------- fused = base * gate (in place) ----------------
__global__ void fuse_scale_kernel(float* __restrict__ base, const float* __restrict__ gp) {
    int r = blockIdx.x;
    float g0 = gp[(size_t)r * 2 + 0];
    float g1 = gp[(size_t)r * 2 + 1];
    float* br = base + (size_t)r * FD_DIM;
    for (int j = threadIdx.x; j < FD_DIM; j += 256) br[j] *= (j < H_DIM) ? g0 : g1;
}

extern "C" void kernel_launch(void* const* d_in, const int* in_sizes, int n_in,
                              void* d_out, int out_size, void* d_ws, size_t ws_size,
                              hipStream_t stream) {
    const float* x = (const float*)d_in[0];
    const float* ln_v_g = (const float*)d_in[1];
    const float* ln_v_b = (const float*)d_in[2];
    const float* ln_t_g = (const float*)d_in[3];
    const float* ln_t_b = (const float*)d_in[4];
    const float* W_v = (const float*)d_in[5];
    const float* b_v = (const float*)d_in[6];
    const float* W_t = (const float*)d_in[7];
    const float* b_t = (const float*)d_in[8];
    const float* W_cp = (const float*)d_in[9];
    const float* b_cp = (const float*)d_in[10];
    const float* W_ctx1 = (const float*)d_in[11];
    const float* b_ctx1 = (const float*)d_in[12];
    const float* W_ctx2 = (const float*)d_in[13];
    const float* b_ctx2 = (const float*)d_in[14];
    const float* W_g1 = (const float*)d_in[15];
    const float* b_g1 = (const float*)d_in[16];
    const float* W_g2 = (const float*)d_in[17];
    const float* b_g2 = (const float*)d_in[18];
    const float* W_gu1 = (const float*)d_in[19];
    const float* b_gu1 = (const float*)d_in[20];
    const float* W_gu2 = (const float*)d_in[21];
    const float* b_gu2 = (const float*)d_in[22];
    const float* W_c1 = (const float*)d_in[23];
    const float* b_c1 = (const float*)d_in[24];
    const float* bn_g = (const float*)d_in[25];
    const float* bn_b = (const float*)d_in[26];
    const float* W_c2 = (const float*)d_in[27];
    const float* b_c2 = (const float*)d_in[28];

    float* out = (float*)d_out;

    // ---- workspace arena (floats) ----
    float* ws = (float*)d_ws;
    size_t off = 0;
    float* xn = ws + off;    off += (size_t)B_ROWS * DV_DIM;   // LN out / gate_in / gu_h
    float* base = ws + off;  off += (size_t)B_ROWS * FD_DIM;   // base_fused, later fused (in place)
    float* agg = ws + off;   off += (size_t)B_ROWS * FD_DIM;   // neigh_agg, later spatial_update
    float* tmpH = ws + off;  off += (size_t)B_ROWS * H_DIM;    // ctx_h / gate_h / h
    float* token = ws + off; off += (size_t)B_ROWS * H_DIM;    // spatial_token
    float* cp = ws + off;    off += (size_t)B_ROWS * C_CLS;    // class_prior
    float* gp = ws + off;    off += (size_t)B_ROWS * 2;        // gate_probs
    float* ent = ws + off;   off += B_ROWS;                    // per-row entropy
    float* cxv = ws + off;   off += B_ROWS;
    float* cyv = ws + off;   off += B_ROWS;
    float* sqv = ws + off;   off += B_ROWS;
    float* wgt = ws + off;   off += (size_t)B_ROWS * K_NN;     // knn softmax weights
    int* ibase = (int*)(ws + off);
    int* imgi = ibase;
    int* cnt = ibase + B_ROWS;
    int* start = cnt + N_IMG;
    int* cursor = start + N_IMG;
    int* perm = cursor + N_IMG;
    int* kidx = perm + B_ROWS;  // B_ROWS * K_NN ints

    dim3 blk(256);
    dim3 gridRows((B_ROWS + 255) / 256);

    // ---- KNN structure (coords/img only; shared by both aggregates) ----
    zero_cnt_kernel<<<1, N_IMG, 0, stream>>>(cnt);
    extract_kernel<<<gridRows, blk, 0, stream>>>(x, cxv, cyv, sqv, imgi, cnt);
    scan_kernel<<<1, N_IMG, 0, stream>>>(cnt, start, cursor);
    scatter_kernel<<<gridRows, blk, 0, stream>>>(imgi, cursor, perm);
    knn_kernel<<<gridRows, blk, 0, stream>>>(cxv, cyv, sqv, imgi, cnt, start, perm, kidx, wgt);

    // ---- fv / ft ----
    ln_kernel<<<B_ROWS, blk, 0, stream>>>(x, 0, DV_DIM, ln_v_g, ln_v_b, xn);
    sgemm_kernel<<<dim3(H_DIM / BN, B_ROWS / BM), blk, 0, stream>>>(
        xn, W_v, base, b_v, nullptr, nullptr, B_ROWS, H_DIM, DV_DIM, FD_DIM, 0, 0.f);
    ln_kernel<<<B_ROWS, blk, 0, stream>>>(x, DV_DIM, DT_DIM, ln_t_g, ln_t_b, xn);
    sgemm_kernel<<<dim3(H_DIM / BN, B_ROWS / BM), blk, 0, stream>>>(
        xn, W_t, base + H_DIM, b_t, nullptr, nullptr, B_ROWS, H_DIM, DT_DIM, FD_DIM, 0, 0.f);

    // ---- class prior ----
    rowvec_kernel<C_CLS, 1><<<B_ROWS / 4, blk, 0, stream>>>(base, FD_DIM, FD_DIM, W_cp, b_cp, cp, C_CLS);

    // ---- neigh_agg over base_fused, spatial token ----
    agg_kernel<<<B_ROWS, blk, 0, stream>>>(base, kidx, wgt, agg);
    sgemm_kernel<<<dim3(H_DIM / BN, B_ROWS / BM), blk, 0, stream>>>(
        agg, W_ctx1, tmpH, b_ctx1, nullptr, nullptr, B_ROWS, H_DIM, FD_DIM, H_DIM, 1, 0.f);
    sgemm_kernel<<<dim3(H_DIM / BN, B_ROWS / BM), blk, 0, stream>>>(
        tmpH, W_ctx2, token, b_ctx2, nullptr, nullptr, B_ROWS, H_DIM, H_DIM, H_DIM, 0, 0.f);

    // ---- gate ----
    concat_kernel<<<B_ROWS, blk, 0, stream>>>(base, cp, token, xn);  // gate_in in xn
    sgemm_kernel<<<dim3(GH_DIM / BN, B_ROWS / BM), blk, 0, stream>>>(
        xn, W_g1, tmpH, b_g1, nullptr, nullptr, B_ROWS, GH_DIM, GI_DIM, GH_DIM, 1, 0.f);
    gate_kernel<<<B_ROWS / 4, blk, 0, stream>>>(tmpH, W_g2, b_g2, gp, ent);
    ent_reduce_kernel<<<1, blk, 0, stream>>>(ent, out + (size_t)B_ROWS * C_CLS);

    // ---- fused = [fv*g0, ft*g1] (in place over base) ----
    fuse_scale_kernel<<<B_ROWS, blk, 0, stream>>>(base, gp);

    // ---- spatial update on fused ----
    agg_kernel<<<B_ROWS, blk, 0, stream>>>(base, kidx, wgt, agg);
    sgemm_kernel<<<dim3(FD_DIM / BN, B_ROWS / BM), blk, 0, stream>>>(
        agg, W_gu1, xn, b_gu1, nullptr, nullptr, B_ROWS, FD_DIM, FD_DIM, FD_DIM, 1, 0.f);  // gu_h in xn
    sgemm_kernel<<<dim3(FD_DIM / BN, B_ROWS / BM), blk, 0, stream>>>(
        xn, W_gu2, base, b_gu2, nullptr, nullptr, B_ROWS, FD_DIM, FD_DIM, FD_DIM, 2, ALPHA_F);  // fused += 0.5*upd

    // ---- classifier head ----
    sgemm_kernel<<<dim3(H_DIM / BN, B_ROWS / BM), blk, 0, stream>>>(
        base, W_c1, tmpH, b_c1, bn_g, bn_b, B_ROWS, H_DIM, FD_DIM, H_DIM, 3, 0.f);
    rowvec_kernel<C_CLS, 0><<<B_ROWS / 4, blk, 0, stream>>>(tmpH, H_DIM, H_DIM, W_c2, b_c2, out, C_CLS);

    (void)in_sizes; (void)n_in; (void)out_size; (void)ws_size;
}

// Round 2
// 524.343 us; speedup vs baseline: 1.9473x; 1.9473x over previous
//
#include <hip/hip_runtime.h>
#include <math.h>

#define B_ROWS 8192
#define DV_DIM 1024
#define DT_DIM 768
#define H_DIM 256
#define C_CLS 5
#define GH_DIM 128
#define K_NN 8
#define FD_DIM 512
#define GIP_DIM 832   /* gate_in padded (773 -> 832, multiple of 64) */
#define GI_REAL 773
#define XCOLS 1797
#define NEGV -1000000000.0f
#define LN_EPS_F 1e-5f
#define BN_EPS_F 1e-5f
#define N_IMG 512
#define EW_F 0.01f
#define ALPHA_F 0.5f

typedef __attribute__((ext_vector_type(8))) short short8v;
typedef __attribute__((ext_vector_type(4))) float float4v;
typedef __attribute__((ext_vector_type(4))) float f32x4;

// ---------------- KNN structure ----------------
__global__ void zero_cnt_kernel(int* cnt) { cnt[threadIdx.x] = 0; }

__global__ void extract_kernel(const float* __restrict__ x,
                               float* __restrict__ cx, float* __restrict__ cy,
                               float* __restrict__ sq, int* __restrict__ imgi,
                               int* __restrict__ cnt) {
    int i = blockIdx.x * blockDim.x + threadIdx.x;
    if (i >= B_ROWS) return;
    const float* row = x + (size_t)i * XCOLS;
    float a = row[DV_DIM + DT_DIM];
    float b = row[DV_DIM + DT_DIM + 1];
    cx[i] = a; cy[i] = b; sq[i] = a * a + b * b;
    int m = (int)row[DV_DIM + DT_DIM + 4];
    imgi[i] = m;
    atomicAdd(&cnt[m], 1);
}

__global__ void scan_kernel(const int* __restrict__ cnt, int* __restrict__ start,
                            int* __restrict__ cursor) {
    __shared__ int s[N_IMG];
    int t = threadIdx.x;
    s[t] = cnt[t];
    __syncthreads();
    for (int off = 1; off < N_IMG; off <<= 1) {
        int v = (t >= off) ? s[t - off] : 0;
        __syncthreads();
        s[t] += v;
        __syncthreads();
    }
    int st = s[t] - cnt[t];
    start[t] = st;
    cursor[t] = st;
}

__global__ void scatter_kernel(const int* __restrict__ imgi, int* __restrict__ cursor,
                               int* __restrict__ perm) {
    int i = blockIdx.x * blockDim.x + threadIdx.x;
    if (i >= B_ROWS) return;
    int pos = atomicAdd(&cursor[imgi[i]], 1);
    perm[pos] = i;
}

__global__ void knn_kernel(const float* __restrict__ cx, const float* __restrict__ cy,
                           const float* __restrict__ sq, const int* __restrict__ imgi,
                           const int* __restrict__ cnt, const int* __restrict__ start,
                           const int* __restrict__ perm, int* __restrict__ knn_idx,
                           float* __restrict__ knn_w) {
    int i = blockIdx.x * blockDim.x + threadIdx.x;
    if (i >= B_ROWS) return;
    float xi = cx[i], yi = cy[i], si = sq[i];
    float vals[K_NN];
    int ids[K_NN];
#pragma unroll
    for (int k = 0; k < K_NN; ++k) { vals[k] = NEGV; ids[k] = i; }
    int m = imgi[i];
    int s = cnt[m];
    if (s >= 2) {
        int st = start[m];
        for (int t = 0; t < s; ++t) {
            int j = perm[st + t];
            if (j == i) continue;
            float d2 = si + sq[j] - 2.f * (xi * cx[j] + yi * cy[j]);
            d2 = fmaxf(d2, 0.f);
            float v = -sqrtf(d2);
            if (v > vals[K_NN - 1]) {
                int p = K_NN - 1;
                while (p > 0 && vals[p - 1] < v) {
                    vals[p] = vals[p - 1]; ids[p] = ids[p - 1]; --p;
                }
                vals[p] = v; ids[p] = j;
            }
        }
    } else {
        for (int j = 0; j < B_ROWS; ++j) {
            if (j == i) continue;
            float d2 = si + sq[j] - 2.f * (xi * cx[j] + yi * cy[j]);
            d2 = fmaxf(d2, 0.f);
            float v = -sqrtf(d2);
            if (v > vals[K_NN - 1]) {
                int p = K_NN - 1;
                while (p > 0 && vals[p - 1] < v) {
                    vals[p] = vals[p - 1]; ids[p] = ids[p - 1]; --p;
                }
                vals[p] = v; ids[p] = j;
            }
        }
    }
    float mx = vals[0];
    float e[K_NN];
    float sum = 0.f;
#pragma unroll
    for (int k = 0; k < K_NN; ++k) { e[k] = expf(vals[k] - mx); sum += e[k]; }
    float inv = 1.f / sum;
#pragma unroll
    for (int k = 0; k < K_NN; ++k) {
        knn_w[(size_t)i * K_NN + k] = e[k] * inv;
        knn_idx[(size_t)i * K_NN + k] = ids[k];
    }
}

// ---------------- layernorm ----------------
__global__ __launch_bounds__(256) void ln_kernel(const float* __restrict__ x, int colOff, int D,
                                                 const float* __restrict__ g,
                                                 const float* __restrict__ b,
                                                 float* __restrict__ y) {
    int row = blockIdx.x;
    const float* xr = x + (size_t)row * XCOLS + colOff;
    float* yr = y + (size_t)row * D;
    float vals[4];
    int n = 0;
    float sum = 0.f;
    for (int j = threadIdx.x; j < D; j += 256) { float v = xr[j]; vals[n++] = v; sum += v; }
    __shared__ float red[256];
    red[threadIdx.x] = sum;
    __syncthreads();
    for (int off = 128; off; off >>= 1) {
        if (threadIdx.x < off) red[threadIdx.x] += red[threadIdx.x + off];
        __syncthreads();
    }
    float mean = red[0] / (float)D;
    __syncthreads();
    float vs = 0.f;
    for (int k = 0; k < n; ++k) { float d = vals[k] - mean; vs += d * d; }
    red[threadIdx.x] = vs;
    __syncthreads();
    for (int off = 128; off; off >>= 1) {
        if (threadIdx.x < off) red[threadIdx.x] += red[threadIdx.x + off];
        __syncthreads();
    }
    float var = red[0] / (float)D;
    float rs = rsqrtf(var + LN_EPS_F);
    int k2 = 0;
    for (int j = threadIdx.x; j < D; j += 256) {
        yr[j] = (vals[k2++] - mean) * rs * g[j] + b[j];
    }
}

// ---------------- weight prep: W[K][N] fp32 -> BT hi/lo [N][Kpad] bf16 ----------------
__global__ void prep_w_kernel(const float* __restrict__ W, short* __restrict__ hi,
                              short* __restrict__ lo, int K, int N, int Kpad) {
    int idx = blockIdx.x * blockDim.x + threadIdx.x;
    if (idx >= N * Kpad) return;
    int n = idx / Kpad, k = idx - n * Kpad;
    float f = (k < K) ? W[(size_t)k * N + n] : 0.f;
    unsigned u = __float_as_uint(f);
    unsigned h = (u + 0x7fffu + ((u >> 16) & 1u)) >> 16;
    float fh = __uint_as_float(h << 16);
    float fl = f - fh;
    unsigned ul = __float_as_uint(fl);
    unsigned l2 = (ul + 0x7fffu + ((ul >> 16) & 1u)) >> 16;
    hi[idx] = (short)h;
    lo[idx] = (short)l2;
}

// ---------------- split-bf16 MFMA GEMM ----------------
// C[M,N] = epi(A[M,K]fp32 @ B[K,N] + bias), B given transposed+split bf16 hi/lo [N][K].
// acc += Ahi*Bhi + Ahi*Blo + Alo*Bhi  (fp32-accurate)
// block 128x64, 4 waves (2x2), wave tile 64x32, BK=64.
#define GBM 128
#define GBN 64
#define GBK 64
#define ASTR 64  /* shorts per LDS row = 128B, 8 chunks of 16B, XOR-swizzled */

__device__ inline void cvt_hilo(const float4v* va, short8v* ah8, short8v* al8) {
#pragma unroll
    for (int c = 0; c < 4; ++c) {
        union { short s[8]; short8v v; } H, L;
#pragma unroll
        for (int j = 0; j < 8; ++j) {
            float f = va[c * 2 + (j >> 2)][j & 3];
            unsigned u = __float_as_uint(f);
            unsigned h = (u + 0x7fffu + ((u >> 16) & 1u)) >> 16;
            float fh = __uint_as_float(h << 16);
            float fl = f - fh;
            unsigned ul = __float_as_uint(fl);
            unsigned l2 = (ul + 0x7fffu + ((ul >> 16) & 1u)) >> 16;
            H.s[j] = (short)h;
            L.s[j] = (short)l2;
        }
        ah8[c] = H.v;
        al8[c] = L.v;
    }
}

__global__ __launch_bounds__(256) void gemm_mfma_kernel(
    const float* __restrict__ A, const short* __restrict__ BThi,
    const short* __restrict__ BTlo, float* __restrict__ C,
    const float* __restrict__ bias, const float* __restrict__ sg,
    const float* __restrict__ sb, int K, int ldc, int mode, float alpha) {
    __shared__ short lds[2 * GBM * ASTR];
    short* Ah = lds;
    short* Al = lds + GBM * ASTR;

    const int tid = threadIdx.x;
    const int lane = tid & 63;
    const int wave = tid >> 6;
    const int wm = wave >> 1, wn = wave & 1;
    const int l15 = lane & 15, lq = lane >> 4;

    const long rowBase = (long)blockIdx.y * GBM;
    const int colBase = blockIdx.x * GBN;

    const int arow = tid >> 1;       // 0..127
    const int ahalf = tid & 1;       // which 32-float half of the row
    const float* gA = A + (rowBase + arow) * (long)K + ahalf * 32;

    float4v va[8];
    short8v ah8[4], al8[4];

    f32x4 acc[4][2];
#pragma unroll
    for (int i = 0; i < 4; ++i)
#pragma unroll
        for (int j = 0; j < 2; ++j) acc[i][j] = (f32x4){0.f, 0.f, 0.f, 0.f};

    // prologue: load + convert tile 0
    {
        const float4v* p = (const float4v*)gA;
#pragma unroll
        for (int i = 0; i < 8; ++i) va[i] = p[i];
        cvt_hilo(va, ah8, al8);
    }

    const int nsteps = K / GBK;
    for (int s = 0; s < nsteps; ++s) {
        __syncthreads();
        {
            // XOR-swizzled write: logical chunk cc -> phys cc ^ (row & 7)
#pragma unroll
            for (int c = 0; c < 4; ++c) {
                int cc = ahalf * 4 + c;
                int off = arow * ASTR + ((cc ^ (arow & 7)) << 3);
                *(short8v*)&Ah[off] = ah8[c];
                *(short8v*)&Al[off] = al8[c];
            }
        }
        __syncthreads();
        if (s + 1 < nsteps) {
            const float4v* p = (const float4v*)(gA + (size_t)(s + 1) * GBK);
#pragma unroll
            for (int i = 0; i < 8; ++i) va[i] = p[i];
        }
#pragma unroll
        for (int ksub = 0; ksub < 2; ++ksub) {
            short8v bfh[2], bfl[2], afh[4], afl[4];
#pragma unroll
            for (int nf = 0; nf < 2; ++nf) {
                long bo = (long)(colBase + wn * 32 + nf * 16 + l15) * K + s * GBK + ksub * 32 + lq * 8;
                bfh[nf] = *(const short8v*)(BThi + bo);
                bfl[nf] = *(const short8v*)(BTlo + bo);
            }
#pragma unroll
            for (int mf = 0; mf < 4; ++mf) {
                int r = wm * 64 + mf * 16 + l15;
                int cc = ksub * 4 + lq;
                int off = r * ASTR + ((cc ^ (r & 7)) << 3);
                afh[mf] = *(short8v*)&Ah[off];
                afl[mf] = *(short8v*)&Al[off];
            }
#pragma unroll
            for (int mf = 0; mf < 4; ++mf)
#pragma unroll
                for (int nf = 0; nf < 2; ++nf) {
                    acc[mf][nf] = __builtin_amdgcn_mfma_f32_16x16x32_bf16(afh[mf], bfh[nf], acc[mf][nf], 0, 0, 0);
                    acc[mf][nf] = __builtin_amdgcn_mfma_f32_16x16x32_bf16(afh[mf], bfl[nf], acc[mf][nf], 0, 0, 0);
                    acc[mf][nf] = __builtin_amdgcn_mfma_f32_16x16x32_bf16(afl[mf], bfh[nf], acc[mf][nf], 0, 0, 0);
                }
        }
        if (s + 1 < nsteps) cvt_hilo(va, ah8, al8);
    }

    // epilogue: D layout col = lane&15, row = (lane>>4)*4 + reg
#pragma unroll
    for (int mf = 0; mf < 4; ++mf)
#pragma unroll
        for (int nf = 0; nf < 2; ++nf) {
            int col = colBase + wn * 32 + nf * 16 + l15;
            long row0 = rowBase + wm * 64 + mf * 16 + lq * 4;
#pragma unroll
            for (int r = 0; r < 4; ++r) {
                long o = (row0 + r) * ldc + col;
                float v = acc[mf][nf][r] + (bias ? bias[col] : 0.f);
                if (mode == 1) {
                    C[o] = fmaxf(v, 0.f);
                } else if (mode == 2) {
                    C[o] = C[o] + alpha * v;
                } else if (mode == 3) {
                    v = v * (sg[col] / sqrtf(1.f + BN_EPS_F)) + sb[col];
                    C[o] = fmaxf(v, 0.f);
                } else {
                    C[o] = v;
                }
            }
        }
}

// ---------------- small-N row matvec ----------------
template <int NOUT, int SOFTMAX>
__global__ __launch_bounds__(256) void rowvec_kernel(const float* __restrict__ X, int ldx, int K,
                                                     const float* __restrict__ W,
                                                     const float* __restrict__ bias,
                                                     float* __restrict__ Y, int ldy) {
    int wave = threadIdx.x >> 6;
    int lane = threadIdx.x & 63;
    int row = blockIdx.x * 4 + wave;
    if (row >= B_ROWS) return;
    const float* xr = X + (size_t)row * ldx;
    float acc[NOUT];
#pragma unroll
    for (int n = 0; n < NOUT; ++n) acc[n] = 0.f;
    for (int k = lane; k < K; k += 64) {
        float xv = xr[k];
#pragma unroll
        for (int n = 0; n < NOUT; ++n) acc[n] = fmaf(xv, W[(size_t)k * NOUT + n], acc[n]);
    }
#pragma unroll
    for (int n = 0; n < NOUT; ++n)
        for (int off = 32; off; off >>= 1) acc[n] += __shfl_down(acc[n], off);
    if (lane == 0) {
#pragma unroll
        for (int n = 0; n < NOUT; ++n) acc[n] += bias[n];
        if (SOFTMAX) {
            float mx = acc[0];
#pragma unroll
            for (int n = 1; n < NOUT; ++n) mx = fmaxf(mx, acc[n]);
            float s = 0.f;
#pragma unroll
            for (int n = 0; n < NOUT; ++n) { acc[n] = expf(acc[n] - mx); s += acc[n]; }
            float inv = 1.f / s;
#pragma unroll
            for (int n = 0; n < NOUT; ++n) acc[n] *= inv;
        }
#pragma unroll
        for (int n = 0; n < NOUT; ++n) Y[(size_t)row * ldy + n] = acc[n];
    }
}

// ---------------- gate head ----------------
__global__ __launch_bounds__(256) void gate_kernel(const float* __restrict__ gh,
                                                   const float* __restrict__ W2,
                                                   const float* __restrict__ b2,
                                                   float* __restrict__ gp,
                                                   float* __restrict__ ent) {
    int wave = threadIdx.x >> 6;
    int lane = threadIdx.x & 63;
    int row = blockIdx.x * 4 + wave;
    if (row >= B_ROWS) return;
    const float* xr = gh + (size_t)row * GH_DIM;
    float a0 = 0.f, a1 = 0.f;
    for (int k = lane; k < GH_DIM; k += 64) {
        float xv = xr[k];
        a0 = fmaf(xv, W2[k * 2 + 0], a0);
        a1 = fmaf(xv, W2[k * 2 + 1], a1);
    }
    for (int off = 32; off; off >>= 1) {
        a0 += __shfl_down(a0, off);
        a1 += __shfl_down(a1, off);
    }
    if (lane == 0) {
        float l0 = a0 + b2[0], l1 = a1 + b2[1];
        float mx = fmaxf(l0, l1);
        float e0 = expf(l0 - mx), e1 = expf(l1 - mx);
        float s = e0 + e1;
        float p0 = e0 / s, p1 = e1 / s;
        gp[(size_t)row * 2 + 0] = p0;
        gp[(size_t)row * 2 + 1] = p1;
        ent[row] = -(p0 * logf(p0 + 1e-8f) + p1 * logf(p1 + 1e-8f));
    }
}

__global__ void ent_reduce_kernel(const float* __restrict__ ent, float* __restrict__ out) {
    __shared__ float red[256];
    float s = 0.f;
    for (int i = threadIdx.x; i < B_ROWS; i += 256) s += ent[i];
    red[threadIdx.x] = s;
    __syncthreads();
    for (int off = 128; off; off >>= 1) {
        if (threadIdx.x < off) red[threadIdx.x] += red[threadIdx.x + off];
        __syncthreads();
    }
    if (threadIdx.x == 0) out[0] = red[0] * (EW_F / (float)B_ROWS);
}

// ---------------- weighted gather aggregate ----------------
__global__ __launch_bounds__(256) void agg_kernel(const float* __restrict__ feat,
                                                  const int* __restrict__ knn_idx,
                                                  const float* __restrict__ knn_w,
                                                  float* __restrict__ out) {
    int row = blockIdx.x;
    int jj[K_NN];
    float ww[K_NN];
#pragma unroll
    for (int k = 0; k < K_NN; ++k) {
        jj[k] = knn_idx[(size_t)row * K_NN + k];
        ww[k] = knn_w[(size_t)row * K_NN + k];
    }
    for (int d = threadIdx.x; d < FD_DIM; d += 256) {
        float s = 0.f;
#pragma unroll
        for (int k = 0; k < K_NN; ++k) s = fmaf(ww[k], feat[(size_t)jj[k] * FD_DIM + d], s);
        out[(size_t)row * FD_DIM + d] = s;
    }
}

// ---------------- gate_in: copy base into [0:512), zero pad [773:832) ----------------
__global__ void concat_pad_kernel(const float* __restrict__ base, float* __restrict__ gi) {
    int r = blockIdx.x;
    const float* br = base + (size_t)r * FD_DIM;
    float* gr = gi + (size_t)r * GIP_DIM;
    for (int j = threadIdx.x; j < FD_DIM; j += 256) gr[j] = br[j];
    for (int j = GI_REAL + threadIdx.x; j < GIP_DIM; j += 256) gr[j] = 0.f;
}

// ---------------- fused = base * gate (in place) ----------------
__global__ void fuse_scale_kernel(float* __restrict__ base, const float* __restrict__ gp) {
    int r = blockIdx.x;
    float g0 = gp[(size_t)r * 2 + 0];
    float g1 = gp[(size_t)r * 2 + 1];
    float* br = base + (size_t)r * FD_DIM;
    for (int j = threadIdx.x; j < FD_DIM; j += 256) br[j] *= (j < H_DIM) ? g0 : g1;
}

extern "C" void kernel_launch(void* const* d_in, const int* in_sizes, int n_in,
                              void* d_out, int out_size, void* d_ws, size_t ws_size,
                              hipStream_t stream) {
    const float* x = (const float*)d_in[0];
    const float* ln_v_g = (const float*)d_in[1];
    const float* ln_v_b = (const float*)d_in[2];
    const float* ln_t_g = (const float*)d_in[3];
    const float* ln_t_b = (const float*)d_in[4];
    const float* W_v = (const float*)d_in[5];
    const float* b_v = (const float*)d_in[6];
    const float* W_t = (const float*)d_in[7];
    const float* b_t = (const float*)d_in[8];
    const float* W_cp = (const float*)d_in[9];
    const float* b_cp = (const float*)d_in[10];
    const float* W_ctx1 = (const float*)d_in[11];
    const float* b_ctx1 = (const float*)d_in[12];
    const float* W_ctx2 = (const float*)d_in[13];
    const float* b_ctx2 = (const float*)d_in[14];
    const float* W_g1 = (const float*)d_in[15];
    const float* b_g1 = (const float*)d_in[16];
    const float* W_g2 = (const float*)d_in[17];
    const float* b_g2 = (const float*)d_in[18];
    const float* W_gu1 = (const float*)d_in[19];
    const float* b_gu1 = (const float*)d_in[20];
    const float* W_gu2 = (const float*)d_in[21];
    const float* b_gu2 = (const float*)d_in[22];
    const float* W_c1 = (const float*)d_in[23];
    const float* b_c1 = (const float*)d_in[24];
    const float* bn_g = (const float*)d_in[25];
    const float* bn_b = (const float*)d_in[26];
    const float* W_c2 = (const float*)d_in[27];
    const float* b_c2 = (const float*)d_in[28];

    float* out = (float*)d_out;

    // ---- workspace arena ----
    float* ws = (float*)d_ws;
    float* base = ws;                              // 8192x512
    float* agg = base + (size_t)B_ROWS * FD_DIM;   // 8192x512
    float* tmpH = agg + (size_t)B_ROWS * FD_DIM;   // 8192x256
    float* xn = tmpH + (size_t)B_ROWS * H_DIM;     // 8192x1024 (LN out; later gi 8192x832; later gu_h 8192x512)
    float* gp = xn + (size_t)B_ROWS * DV_DIM;      // 8192x2
    float* ent = gp + (size_t)B_ROWS * 2;          // 8192
    float* cxv = ent + B_ROWS;
    float* cyv = cxv + B_ROWS;
    float* sqv = cyv + B_ROWS;
    float* wgt = sqv + B_ROWS;                     // 8192x8
    int* imgi = (int*)(wgt + (size_t)B_ROWS * K_NN);
    int* cnt = imgi + B_ROWS;
    int* startb = cnt + N_IMG;
    int* cursor = startb + N_IMG;
    int* perm = cursor + N_IMG;
    int* kidx = perm + B_ROWS;                     // 8192x8 ints
    short* wsh = (short*)(kidx + (size_t)B_ROWS * K_NN);
    // weight segments (shorts): [N][Kpad] each, hi then lo
    short* wv_h = wsh;                         short* wv_l = wv_h + 256 * 1024;
    short* wt_h = wv_l + 256 * 1024;           short* wt_l = wt_h + 256 * 768;
    short* wx1_h = wt_l + 256 * 768;           short* wx1_l = wx1_h + 256 * 512;
    short* wx2_h = wx1_l + 256 * 512;          short* wx2_l = wx2_h + 256 * 256;
    short* wg1_h = wx2_l + 256 * 256;          short* wg1_l = wg1_h + 128 * GIP_DIM;
    short* wu1_h = wg1_l + 128 * GIP_DIM;      short* wu1_l = wu1_h + 512 * 512;
    short* wu2_h = wu1_l + 512 * 512;          short* wu2_l = wu2_h + 512 * 512;
    short* wc1_h = wu2_l + 512 * 512;          short* wc1_l = wc1_h + 256 * 512;

    float* gi = xn;  // 8192 x 832 view (xn is free after the ft GEMM)

    dim3 blk(256);
    dim3 gridRows((B_ROWS + 255) / 256);

    // ---- weight prep (inputs only; no deps) ----
    prep_w_kernel<<<(256 * 1024 + 255) / 256, blk, 0, stream>>>(W_v, wv_h, wv_l, 1024, 256, 1024);
    prep_w_kernel<<<(256 * 768 + 255) / 256, blk, 0, stream>>>(W_t, wt_h, wt_l, 768, 256, 768);
    prep_w_kernel<<<(256 * 512 + 255) / 256, blk, 0, stream>>>(W_ctx1, wx1_h, wx1_l, 512, 256, 512);
    prep_w_kernel<<<(256 * 256 + 255) / 256, blk, 0, stream>>>(W_ctx2, wx2_h, wx2_l, 256, 256, 256);
    prep_w_kernel<<<(128 * GIP_DIM + 255) / 256, blk, 0, stream>>>(W_g1, wg1_h, wg1_l, GI_REAL, 128, GIP_DIM);
    prep_w_kernel<<<(512 * 512 + 255) / 256, blk, 0, stream>>>(W_gu1, wu1_h, wu1_l, 512, 512, 512);
    prep_w_kernel<<<(512 * 512 + 255) / 256, blk, 0, stream>>>(W_gu2, wu2_h, wu2_l, 512, 512, 512);
    prep_w_kernel<<<(256 * 512 + 255) / 256, blk, 0, stream>>>(W_c1, wc1_h, wc1_l, 512, 256, 512);

    // ---- KNN structure ----
    zero_cnt_kernel<<<1, N_IMG, 0, stream>>>(cnt);
    extract_kernel<<<gridRows, blk, 0, stream>>>(x, cxv, cyv, sqv, imgi, cnt);
    scan_kernel<<<1, N_IMG, 0, stream>>>(cnt, startb, cursor);
    scatter_kernel<<<gridRows, blk, 0, stream>>>(imgi, cursor, perm);
    knn_kernel<<<gridRows, blk, 0, stream>>>(cxv, cyv, sqv, imgi, cnt, startb, perm, kidx, wgt);

    // ---- fv / ft ----
    ln_kernel<<<B_ROWS, blk, 0, stream>>>(x, 0, DV_DIM, ln_v_g, ln_v_b, xn);
    gemm_mfma_kernel<<<dim3(H_DIM / GBN, B_ROWS / GBM), blk, 0, stream>>>(
        xn, wv_h, wv_l, base, b_v, nullptr, nullptr, DV_DIM, FD_DIM, 0, 0.f);
    ln_kernel<<<B_ROWS, blk, 0, stream>>>(x, DV_DIM, DT_DIM, ln_t_g, ln_t_b, xn);
    gemm_mfma_kernel<<<dim3(H_DIM / GBN, B_ROWS / GBM), blk, 0, stream>>>(
        xn, wt_h, wt_l, base + H_DIM, b_t, nullptr, nullptr, DT_DIM, FD_DIM, 0, 0.f);

    // ---- class prior -> gi[:, 512:517] ----
    rowvec_kernel<C_CLS, 1><<<B_ROWS / 4, blk, 0, stream>>>(base, FD_DIM, FD_DIM, W_cp, b_cp, gi + FD_DIM, GIP_DIM);

    // ---- neigh_agg, spatial token -> gi[:, 517:773] ----
    agg_kernel<<<B_ROWS, blk, 0, stream>>>(base, kidx, wgt, agg);
    gemm_mfma_kernel<<<dim3(H_DIM / GBN, B_ROWS / GBM), blk, 0, stream>>>(
        agg, wx1_h, wx1_l, tmpH, b_ctx1, nullptr, nullptr, FD_DIM, H_DIM, 1, 0.f);
    gemm_mfma_kernel<<<dim3(H_DIM / GBN, B_ROWS / GBM), blk, 0, stream>>>(
        tmpH, wx2_h, wx2_l, gi + FD_DIM + C_CLS, b_ctx2, nullptr, nullptr, H_DIM, GIP_DIM, 0, 0.f);

    // ---- gate ----
    concat_pad_kernel<<<B_ROWS, blk, 0, stream>>>(base, gi);
    gemm_mfma_kernel<<<dim3(GH_DIM / GBN, B_ROWS / GBM), blk, 0, stream>>>(
        gi, wg1_h, wg1_l, tmpH, b_g1, nullptr, nullptr, GIP_DIM, GH_DIM, 1, 0.f);
    gate_kernel<<<B_ROWS / 4, blk, 0, stream>>>(tmpH, W_g2, b_g2, gp, ent);
    ent_reduce_kernel<<<1, blk, 0, stream>>>(ent, out + (size_t)B_ROWS * C_CLS);

    // ---- fused = [fv*g0, ft*g1] ----
    fuse_scale_kernel<<<B_ROWS, blk, 0, stream>>>(base, gp);

    // ---- spatial update ----
    agg_kernel<<<B_ROWS, blk, 0, stream>>>(base, kidx, wgt, agg);
    gemm_mfma_kernel<<<dim3(FD_DIM / GBN, B_ROWS / GBM), blk, 0, stream>>>(
        agg, wu1_h, wu1_l, xn, b_gu1, nullptr, nullptr, FD_DIM, FD_DIM, 1, 0.f);  // gu_h in xn
    gemm_mfma_kernel<<<dim3(FD_DIM / GBN, B_ROWS / GBM), blk, 0, stream>>>(
        xn, wu2_h, wu2_l, base, b_gu2, nullptr, nullptr, FD_DIM, FD_DIM, 2, ALPHA_F);

    // ---- classifier head ----
    gemm_mfma_kernel<<<dim3(H_DIM / GBN, B_ROWS / GBM), blk, 0, stream>>>(
        base, wc1_h, wc1_l, tmpH, b_c1, bn_g, bn_b, FD_DIM, H_DIM, 3, 0.f);
    rowvec_kernel<C_CLS, 0><<<B_ROWS / 4, blk, 0, stream>>>(tmpH, H_DIM, H_DIM, W_c2, b_c2, out, C_CLS);

    (void)in_sizes; (void)n_in; (void)out_size; (void)ws_size;
}

// Round 3
// 284.856 us; speedup vs baseline: 3.5845x; 1.8407x over previous
//
#include <hip/hip_runtime.h>
#include <math.h>

#define B_ROWS 8192
#define DV_DIM 1024
#define DT_DIM 768
#define H_DIM 256
#define C_CLS 5
#define GH_DIM 128
#define K_NN 8
#define FD_DIM 512
#define GIP_DIM 832
#define GI_REAL 773
#define XCOLS 1797
#define NEGV -1000000000.0f
#define LN_EPS_F 1e-5f
#define BN_EPS_F 1e-5f
#define N_IMG 512
#define EW_F 0.01f
#define ALPHA_F 0.5f

typedef __attribute__((ext_vector_type(8))) short short8v;
typedef __attribute__((ext_vector_type(4))) float f32x4;

__device__ inline void split2(float f, short* h, short* l) {
    unsigned u = __float_as_uint(f);
    unsigned uh = (u + 0x7fffu + ((u >> 16) & 1u)) >> 16;
    float fh = __uint_as_float(uh << 16);
    float fl = f - fh;
    unsigned ul = __float_as_uint(fl);
    *h = (short)uh;
    *l = (short)((ul + 0x7fffu + ((ul >> 16) & 1u)) >> 16);
}

// ---------------- batched weight prep: W[K][N] fp32 -> [N][Kpad] bf16 hi/lo ----------------
struct PrepArgs {
    const float* W[8];
    short* h[8];
    short* l[8];
    int K[8];
    int N[8];
    int Kpad[8];
    int cnt[8];
};

__global__ void prep_all_kernel(PrepArgs a) {
    int idx = blockIdx.x * blockDim.x + threadIdx.x;
#pragma unroll
    for (int s = 0; s < 8; ++s) {
        if (idx < a.cnt[s]) {
            int Kp = a.Kpad[s];
            int n = idx / Kp, k = idx - n * Kp;
            float f = (k < a.K[s]) ? a.W[s][(size_t)k * a.N[s] + n] : 0.f;
            split2(f, &a.h[s][idx], &a.l[s][idx]);
            return;
        }
        idx -= a.cnt[s];
    }
}

// ---------------- KNN structure ----------------
__global__ void extract_kernel(const float* __restrict__ x,
                               float* __restrict__ cx, float* __restrict__ cy,
                               float* __restrict__ sq, int* __restrict__ imgi,
                               int* __restrict__ cnt) {
    int i = blockIdx.x * blockDim.x + threadIdx.x;
    if (i >= B_ROWS) return;
    const float* row = x + (size_t)i * XCOLS;
    float a = row[DV_DIM + DT_DIM];
    float b = row[DV_DIM + DT_DIM + 1];
    cx[i] = a; cy[i] = b; sq[i] = a * a + b * b;
    int m = (int)row[DV_DIM + DT_DIM + 4];
    imgi[i] = m;
    atomicAdd(&cnt[m], 1);
}

__global__ void scan_kernel(const int* __restrict__ cnt, int* __restrict__ start,
                            int* __restrict__ cursor) {
    __shared__ int s[N_IMG];
    int t = threadIdx.x;
    s[t] = cnt[t];
    __syncthreads();
    for (int off = 1; off < N_IMG; off <<= 1) {
        int v = (t >= off) ? s[t - off] : 0;
        __syncthreads();
        s[t] += v;
        __syncthreads();
    }
    int st = s[t] - cnt[t];
    start[t] = st;
    cursor[t] = st;
}

__global__ void scatter_kernel(const int* __restrict__ imgi, int* __restrict__ cursor,
                               int* __restrict__ perm) {
    int i = blockIdx.x * blockDim.x + threadIdx.x;
    if (i >= B_ROWS) return;
    int pos = atomicAdd(&cursor[imgi[i]], 1);
    perm[pos] = i;
}

__global__ void knn_kernel(const float* __restrict__ cx, const float* __restrict__ cy,
                           const float* __restrict__ sq, const int* __restrict__ imgi,
                           const int* __restrict__ cnt, const int* __restrict__ start,
                           const int* __restrict__ perm, int* __restrict__ knn_idx,
                           float* __restrict__ knn_w) {
    int i = blockIdx.x * blockDim.x + threadIdx.x;
    if (i >= B_ROWS) return;
    float xi = cx[i], yi = cy[i], si = sq[i];
    float vals[K_NN];
    int ids[K_NN];
#pragma unroll
    for (int k = 0; k < K_NN; ++k) { vals[k] = NEGV; ids[k] = i; }
    int m = imgi[i];
    int s = cnt[m];
    if (s >= 2) {
        int st = start[m];
        for (int t = 0; t < s; ++t) {
            int j = perm[st + t];
            if (j == i) continue;
            float d2 = si + sq[j] - 2.f * (xi * cx[j] + yi * cy[j]);
            d2 = fmaxf(d2, 0.f);
            float v = -sqrtf(d2);
            if (v > vals[K_NN - 1]) {
                int p = K_NN - 1;
                while (p > 0 && vals[p - 1] < v) {
                    vals[p] = vals[p - 1]; ids[p] = ids[p - 1]; --p;
                }
                vals[p] = v; ids[p] = j;
            }
        }
    } else {
        for (int j = 0; j < B_ROWS; ++j) {
            if (j == i) continue;
            float d2 = si + sq[j] - 2.f * (xi * cx[j] + yi * cy[j]);
            d2 = fmaxf(d2, 0.f);
            float v = -sqrtf(d2);
            if (v > vals[K_NN - 1]) {
                int p = K_NN - 1;
                while (p > 0 && vals[p - 1] < v) {
                    vals[p] = vals[p - 1]; ids[p] = ids[p - 1]; --p;
                }
                vals[p] = v; ids[p] = j;
            }
        }
    }
    float mx = vals[0];
    float e[K_NN];
    float sum = 0.f;
#pragma unroll
    for (int k = 0; k < K_NN; ++k) { e[k] = expf(vals[k] - mx); sum += e[k]; }
    float inv = 1.f / sum;
#pragma unroll
    for (int k = 0; k < K_NN; ++k) {
        knn_w[(size_t)i * K_NN + k] = e[k] * inv;
        knn_idx[(size_t)i * K_NN + k] = ids[k];
    }
}

// ---------------- fused layernorm + hi/lo split for both segments ----------------
__global__ __launch_bounds__(256) void ln_split_kernel(
    const float* __restrict__ x,
    const float* __restrict__ gv, const float* __restrict__ bv,
    const float* __restrict__ gt, const float* __restrict__ bt,
    short* __restrict__ xvh, short* __restrict__ xvl,
    short* __restrict__ xth, short* __restrict__ xtl) {
    int row = blockIdx.x;
    int t = threadIdx.x;
    const float* xr = x + (size_t)row * XCOLS;
    __shared__ float red[256];

    // ---- v segment (1024) ----
    float v[4];
#pragma unroll
    for (int k = 0; k < 4; ++k) v[k] = xr[t + k * 256];
    float sum = v[0] + v[1] + v[2] + v[3];
    red[t] = sum;
    __syncthreads();
    for (int off = 128; off; off >>= 1) {
        if (t < off) red[t] += red[t + off];
        __syncthreads();
    }
    float mean = red[0] * (1.f / DV_DIM);
    __syncthreads();
    float vs = 0.f;
#pragma unroll
    for (int k = 0; k < 4; ++k) { float d = v[k] - mean; vs += d * d; }
    red[t] = vs;
    __syncthreads();
    for (int off = 128; off; off >>= 1) {
        if (t < off) red[t] += red[t + off];
        __syncthreads();
    }
    float rs = rsqrtf(red[0] * (1.f / DV_DIM) + LN_EPS_F);
#pragma unroll
    for (int k = 0; k < 4; ++k) {
        int j = t + k * 256;
        float y = (v[k] - mean) * rs * gv[j] + bv[j];
        split2(y, &xvh[(size_t)row * DV_DIM + j], &xvl[(size_t)row * DV_DIM + j]);
    }
    __syncthreads();

    // ---- t segment (768) ----
    float u[3];
#pragma unroll
    for (int k = 0; k < 3; ++k) u[k] = xr[DV_DIM + t + k * 256];
    sum = u[0] + u[1] + u[2];
    red[t] = sum;
    __syncthreads();
    for (int off = 128; off; off >>= 1) {
        if (t < off) red[t] += red[t + off];
        __syncthreads();
    }
    mean = red[0] * (1.f / DT_DIM);
    __syncthreads();
    vs = 0.f;
#pragma unroll
    for (int k = 0; k < 3; ++k) { float d = u[k] - mean; vs += d * d; }
    red[t] = vs;
    __syncthreads();
    for (int off = 128; off; off >>= 1) {
        if (t < off) red[t] += red[t + off];
        __syncthreads();
    }
    rs = rsqrtf(red[0] * (1.f / DT_DIM) + LN_EPS_F);
#pragma unroll
    for (int k = 0; k < 3; ++k) {
        int j = t + k * 256;
        float y = (u[k] - mean) * rs * gt[j] + bt[j];
        split2(y, &xth[(size_t)row * DT_DIM + j], &xtl[(size_t)row * DT_DIM + j]);
    }
}

// ---------------- split-bf16 MFMA GEMM, both operands LDS-staged ----------------
// tile 64x128, 4 waves (2x2), wave tile 32x64, BK=64. A[M][K], B[N][K] hi/lo bf16.
// MODE 0: Cf = acc+bias           (fv/ft -> base)
// MODE 1: Cf = relu(acc+bias)     (g1 -> gateh)
// MODE 2: Cf = relu((acc+bias)*bnscale + bnb)  (c1 -> h)
// MODE 3: Ch/Cl = split(relu(acc+bias))        (ctx1, gu1)
// MODE 4: Ch/Cl = split(acc+bias)              (ctx2 -> gi)
// MODE 5: Ch/Cl = split(base*gate + 0.5*(acc+bias))  (gu2 -> fused)
template <int MODE>
__global__ __launch_bounds__(256) void gemm2_kernel(
    const short* __restrict__ Ah_g, const short* __restrict__ Al_g, int K,
    const short* __restrict__ Bh_g, const short* __restrict__ Bl_g, int ncb,
    float* __restrict__ Cf, short* __restrict__ Ch, short* __restrict__ Cl,
    int ldc, int colOff, const float* __restrict__ bias,
    const float* __restrict__ aux1, const float* __restrict__ aux2) {
    __shared__ short lds[24576];  // 48KB
    short* sAh = lds;
    short* sAl = lds + 4096;
    short* sBh = lds + 8192;
    short* sBl = lds + 16384;

    const int tid = threadIdx.x;
    const int lane = tid & 63;
    const int wave = tid >> 6;
    const int wm = wave >> 1, wn = wave & 1;
    const int l15 = lane & 15, lq = lane >> 4;

    // bijective XCD swizzle (m204)
    int nwg = gridDim.x;
    int wg = blockIdx.x;
    int q = nwg >> 3, r = nwg & 7;
    int xc = wg & 7, ii = wg >> 3;
    int wid = (xc < r ? xc * (q + 1) : r * (q + 1) + (xc - r) * q) + ii;
    const int panel = wid / ncb, cb = wid - panel * ncb;
    const long rowBase = (long)panel * 64;
    const int colBase = cb * 128;

    f32x4 acc[2][4];
#pragma unroll
    for (int i = 0; i < 2; ++i)
#pragma unroll
        for (int j = 0; j < 4; ++j) acc[i][j] = (f32x4){0.f, 0.f, 0.f, 0.f};

    short8v pAh[2], pAl[2], pBh[4], pBl[4];

    // A chunk ids: tid, tid+256 (512 chunks); B: tid+256*j, j=0..3 (1024 chunks)
    const int ar0 = tid >> 3, ac0 = tid & 7;
    const int ar1 = (tid + 256) >> 3, ac1 = tid & 7;  // (tid+256)&7 == tid&7

    // prologue: load tile 0
    {
        long go0 = (rowBase + ar0) * K + ac0 * 8;
        long go1 = (rowBase + ar1) * K + ac1 * 8;
        pAh[0] = *(const short8v*)(Ah_g + go0);
        pAl[0] = *(const short8v*)(Al_g + go0);
        pAh[1] = *(const short8v*)(Ah_g + go1);
        pAl[1] = *(const short8v*)(Al_g + go1);
#pragma unroll
        for (int j = 0; j < 4; ++j) {
            int cid = tid + 256 * j;
            int cl = cid >> 3, c = cid & 7;
            long go = (colBase + cl) * (long)K + c * 8;
            pBh[j] = *(const short8v*)(Bh_g + go);
            pBl[j] = *(const short8v*)(Bl_g + go);
        }
    }

    const int nsteps = K >> 6;
    for (int s = 0; s < nsteps; ++s) {
        __syncthreads();
        // ds_write tile s (XOR-swizzled 16B chunks within 128B rows)
        {
            int off0 = ar0 * 64 + ((ac0 ^ (ar0 & 7)) << 3);
            int off1 = ar1 * 64 + ((ac1 ^ (ar1 & 7)) << 3);
            *(short8v*)(sAh + off0) = pAh[0];
            *(short8v*)(sAl + off0) = pAl[0];
            *(short8v*)(sAh + off1) = pAh[1];
            *(short8v*)(sAl + off1) = pAl[1];
#pragma unroll
            for (int j = 0; j < 4; ++j) {
                int cid = tid + 256 * j;
                int cl = cid >> 3, c = cid & 7;
                int off = cl * 64 + ((c ^ (cl & 7)) << 3);
                *(short8v*)(sBh + off) = pBh[j];
                *(short8v*)(sBl + off) = pBl[j];
            }
        }
        __syncthreads();
        // prefetch tile s+1 into registers (overlaps MFMA below)
        if (s + 1 < nsteps) {
            long ko = (long)(s + 1) * 64;
            long go0 = (rowBase + ar0) * K + ko + ac0 * 8;
            long go1 = (rowBase + ar1) * K + ko + ac1 * 8;
            pAh[0] = *(const short8v*)(Ah_g + go0);
            pAl[0] = *(const short8v*)(Al_g + go0);
            pAh[1] = *(const short8v*)(Ah_g + go1);
            pAl[1] = *(const short8v*)(Al_g + go1);
#pragma unroll
            for (int j = 0; j < 4; ++j) {
                int cid = tid + 256 * j;
                int cl = cid >> 3, c = cid & 7;
                long go = (colBase + cl) * (long)K + ko + c * 8;
                pBh[j] = *(const short8v*)(Bh_g + go);
                pBl[j] = *(const short8v*)(Bl_g + go);
            }
        }
        // compute
#pragma unroll
        for (int ksub = 0; ksub < 2; ++ksub) {
            int cc = ksub * 4 + lq;
            short8v afh[2], afl[2], bfh[4], bfl[4];
#pragma unroll
            for (int mf = 0; mf < 2; ++mf) {
                int rr = wm * 32 + mf * 16 + l15;
                int off = rr * 64 + ((cc ^ (rr & 7)) << 3);
                afh[mf] = *(short8v*)(sAh + off);
                afl[mf] = *(short8v*)(sAl + off);
            }
#pragma unroll
            for (int nf = 0; nf < 4; ++nf) {
                int cl = wn * 64 + nf * 16 + l15;
                int off = cl * 64 + ((cc ^ (cl & 7)) << 3);
                bfh[nf] = *(short8v*)(sBh + off);
                bfl[nf] = *(short8v*)(sBl + off);
            }
#pragma unroll
            for (int mf = 0; mf < 2; ++mf)
#pragma unroll
                for (int nf = 0; nf < 4; ++nf) {
                    acc[mf][nf] = __builtin_amdgcn_mfma_f32_16x16x32_bf16(afh[mf], bfh[nf], acc[mf][nf], 0, 0, 0);
                    acc[mf][nf] = __builtin_amdgcn_mfma_f32_16x16x32_bf16(afl[mf], bfh[nf], acc[mf][nf], 0, 0, 0);
                    acc[mf][nf] = __builtin_amdgcn_mfma_f32_16x16x32_bf16(afh[mf], bfl[nf], acc[mf][nf], 0, 0, 0);
                }
        }
    }

    // epilogue: C/D layout col = lane&15, row = (lane>>4)*4 + reg
#pragma unroll
    for (int mf = 0; mf < 2; ++mf)
#pragma unroll
        for (int nf = 0; nf < 4; ++nf) {
            int col = colBase + wn * 64 + nf * 16 + l15;
            long row0 = rowBase + wm * 32 + mf * 16 + lq * 4;
#pragma unroll
            for (int rr = 0; rr < 4; ++rr) {
                long row = row0 + rr;
                float v = acc[mf][nf][rr] + bias[col];
                if (MODE == 0) {
                    Cf[row * ldc + colOff + col] = v;
                } else if (MODE == 1) {
                    Cf[row * ldc + colOff + col] = fmaxf(v, 0.f);
                } else if (MODE == 2) {
                    v = v * (aux1[col] * rsqrtf(1.f + BN_EPS_F)) + aux2[col];
                    Cf[row * ldc + colOff + col] = fmaxf(v, 0.f);
                } else if (MODE == 3) {
                    v = fmaxf(v, 0.f);
                    size_t o = (size_t)row * ldc + colOff + col;
                    split2(v, &Ch[o], &Cl[o]);
                } else if (MODE == 4) {
                    size_t o = (size_t)row * ldc + colOff + col;
                    split2(v, &Ch[o], &Cl[o]);
                } else {  // MODE 5: fused = base*gate + 0.5*(acc+bias)
                    float g = aux2[row * 2 + (col >= H_DIM ? 1 : 0)];
                    float fv = aux1[row * FD_DIM + col] * g + ALPHA_F * v;
                    size_t o = (size_t)row * ldc + col;
                    split2(fv, &Ch[o], &Cl[o]);
                }
            }
        }
}

// ---------------- weighted gather (optionally gate-scaled), writes hi/lo ----------------
template <int GATE>
__global__ __launch_bounds__(256) void gather_kernel(const float* __restrict__ feat,
                                                     const int* __restrict__ knn_idx,
                                                     const float* __restrict__ knn_w,
                                                     const float* __restrict__ gp,
                                                     short* __restrict__ oh,
                                                     short* __restrict__ ol) {
    int row = blockIdx.x;
    int t = threadIdx.x;
    int jj[K_NN];
    float ww[K_NN], g0[K_NN], g1[K_NN];
#pragma unroll
    for (int k = 0; k < K_NN; ++k) {
        jj[k] = knn_idx[(size_t)row * K_NN + k];
        ww[k] = knn_w[(size_t)row * K_NN + k];
        if (GATE) {
            g0[k] = gp[(size_t)jj[k] * 2 + 0];
            g1[k] = gp[(size_t)jj[k] * 2 + 1];
        }
    }
#pragma unroll
    for (int half = 0; half < 2; ++half) {
        int d = t + half * 256;
        float s = 0.f;
#pragma unroll
        for (int k = 0; k < K_NN; ++k) {
            float f = feat[(size_t)jj[k] * FD_DIM + d];
            if (GATE) f *= (d < H_DIM) ? g0[k] : g1[k];
            s = fmaf(ww[k], f, s);
        }
        split2(s, &oh[(size_t)row * FD_DIM + d], &ol[(size_t)row * FD_DIM + d]);
    }
}

// ---------------- class prior + gi concat (cols 0-516, zero pad 773-831) ----------------
__global__ __launch_bounds__(256) void cpcat_kernel(const float* __restrict__ base,
                                                    const float* __restrict__ Wcp,
                                                    const float* __restrict__ bcp,
                                                    short* __restrict__ gih,
                                                    short* __restrict__ gil) {
    int row = blockIdx.x;
    int t = threadIdx.x;
    float a = base[(size_t)row * FD_DIM + t];
    float b = base[(size_t)row * FD_DIM + t + 256];
    float acc[C_CLS];
#pragma unroll
    for (int n = 0; n < C_CLS; ++n)
        acc[n] = a * Wcp[t * C_CLS + n] + b * Wcp[(t + 256) * C_CLS + n];
    __shared__ float red[256];
    __shared__ float lg[C_CLS];
#pragma unroll
    for (int n = 0; n < C_CLS; ++n) {
        red[t] = acc[n];
        __syncthreads();
        for (int off = 128; off; off >>= 1) {
            if (t < off) red[t] += red[t + off];
            __syncthreads();
        }
        if (t == 0) lg[n] = red[0] + bcp[n];
        __syncthreads();
    }
    size_t go = (size_t)row * GIP_DIM;
    if (t == 0) {
        float mx = lg[0];
#pragma unroll
        for (int n = 1; n < C_CLS; ++n) mx = fmaxf(mx, lg[n]);
        float s = 0.f;
        float e[C_CLS];
#pragma unroll
        for (int n = 0; n < C_CLS; ++n) { e[n] = expf(lg[n] - mx); s += e[n]; }
        float inv = 1.f / s;
#pragma unroll
        for (int n = 0; n < C_CLS; ++n)
            split2(e[n] * inv, &gih[go + FD_DIM + n], &gil[go + FD_DIM + n]);
    }
    split2(a, &gih[go + t], &gil[go + t]);
    split2(b, &gih[go + t + 256], &gil[go + t + 256]);
    if (t < GIP_DIM - GI_REAL) {
        gih[go + GI_REAL + t] = 0;
        gil[go + GI_REAL + t] = 0;
    }
}

// ---------------- gate head ----------------
__global__ __launch_bounds__(256) void gate_kernel(const float* __restrict__ gh,
                                                   const float* __restrict__ W2,
                                                   const float* __restrict__ b2,
                                                   float* __restrict__ gp,
                                                   float* __restrict__ ent) {
    int wave = threadIdx.x >> 6;
    int lane = threadIdx.x & 63;
    int row = blockIdx.x * 4 + wave;
    if (row >= B_ROWS) return;
    const float* xr = gh + (size_t)row * GH_DIM;
    float a0 = 0.f, a1 = 0.f;
    for (int k = lane; k < GH_DIM; k += 64) {
        float xv = xr[k];
        a0 = fmaf(xv, W2[k * 2 + 0], a0);
        a1 = fmaf(xv, W2[k * 2 + 1], a1);
    }
    for (int off = 32; off; off >>= 1) {
        a0 += __shfl_down(a0, off);
        a1 += __shfl_down(a1, off);
    }
    if (lane == 0) {
        float l0 = a0 + b2[0], l1 = a1 + b2[1];
        float mx = fmaxf(l0, l1);
        float e0 = expf(l0 - mx), e1 = expf(l1 - mx);
        float s = e0 + e1;
        float p0 = e0 / s, p1 = e1 / s;
        gp[(size_t)row * 2 + 0] = p0;
        gp[(size_t)row * 2 + 1] = p1;
        ent[row] = -(p0 * logf(p0 + 1e-8f) + p1 * logf(p1 + 1e-8f));
    }
}

__global__ void ent_reduce_kernel(const float* __restrict__ ent, float* __restrict__ out) {
    __shared__ float red[256];
    float s = 0.f;
    for (int i = threadIdx.x; i < B_ROWS; i += 256) s += ent[i];
    red[threadIdx.x] = s;
    __syncthreads();
    for (int off = 128; off; off >>= 1) {
        if (threadIdx.x < off) red[threadIdx.x] += red[threadIdx.x + off];
        __syncthreads();
    }
    if (threadIdx.x == 0) out[0] = red[0] * (EW_F / (float)B_ROWS);
}

// ---------------- small-N row matvec (final logits) ----------------
template <int NOUT>
__global__ __launch_bounds__(256) void rowvec_kernel(const float* __restrict__ X, int ldx, int K,
                                                     const float* __restrict__ W,
                                                     const float* __restrict__ bias,
                                                     float* __restrict__ Y, int ldy) {
    int wave = threadIdx.x >> 6;
    int lane = threadIdx.x & 63;
    int row = blockIdx.x * 4 + wave;
    if (row >= B_ROWS) return;
    const float* xr = X + (size_t)row * ldx;
    float acc[NOUT];
#pragma unroll
    for (int n = 0; n < NOUT; ++n) acc[n] = 0.f;
    for (int k = lane; k < K; k += 64) {
        float xv = xr[k];
#pragma unroll
        for (int n = 0; n < NOUT; ++n) acc[n] = fmaf(xv, W[(size_t)k * NOUT + n], acc[n]);
    }
#pragma unroll
    for (int n = 0; n < NOUT; ++n)
        for (int off = 32; off; off >>= 1) acc[n] += __shfl_down(acc[n], off);
    if (lane == 0) {
#pragma unroll
        for (int n = 0; n < NOUT; ++n) Y[(size_t)row * ldy + n] = acc[n] + bias[n];
    }
}

extern "C" void kernel_launch(void* const* d_in, const int* in_sizes, int n_in,
                              void* d_out, int out_size, void* d_ws, size_t ws_size,
                              hipStream_t stream) {
    const float* x = (const float*)d_in[0];
    const float* ln_v_g = (const float*)d_in[1];
    const float* ln_v_b = (const float*)d_in[2];
    const float* ln_t_g = (const float*)d_in[3];
    const float* ln_t_b = (const float*)d_in[4];
    const float* W_v = (const float*)d_in[5];
    const float* b_v = (const float*)d_in[6];
    const float* W_t = (const float*)d_in[7];
    const float* b_t = (const float*)d_in[8];
    const float* W_cp = (const float*)d_in[9];
    const float* b_cp = (const float*)d_in[10];
    const float* W_ctx1 = (const float*)d_in[11];
    const float* b_ctx1 = (const float*)d_in[12];
    const float* W_ctx2 = (const float*)d_in[13];
    const float* b_ctx2 = (const float*)d_in[14];
    const float* W_g1 = (const float*)d_in[15];
    const float* b_g1 = (const float*)d_in[16];
    const float* W_g2 = (const float*)d_in[17];
    const float* b_g2 = (const float*)d_in[18];
    const float* W_gu1 = (const float*)d_in[19];
    const float* b_gu1 = (const float*)d_in[20];
    const float* W_gu2 = (const float*)d_in[21];
    const float* b_gu2 = (const float*)d_in[22];
    const float* W_c1 = (const float*)d_in[23];
    const float* b_c1 = (const float*)d_in[24];
    const float* bn_g = (const float*)d_in[25];
    const float* bn_b = (const float*)d_in[26];
    const float* W_c2 = (const float*)d_in[27];
    const float* b_c2 = (const float*)d_in[28];

    float* out = (float*)d_out;

    // ---- workspace arena (byte offsets, 256B aligned) ----
    char* wsb = (char*)d_ws;
    size_t off = 0;
    auto alloc = [&](size_t bytes) {
        char* p = wsb + off;
        off += (bytes + 255) & ~(size_t)255;
        return p;
    };
    float* base = (float*)alloc((size_t)B_ROWS * FD_DIM * 4);       // 16MB, persists
    short* aggh = (short*)alloc((size_t)B_ROWS * FD_DIM * 2);       // 8MB (also fused_h)
    short* aggl = (short*)alloc((size_t)B_ROWS * FD_DIM * 2);       // 8MB (also fused_l)
    char* tmpRegion = alloc((size_t)B_ROWS * H_DIM * 4);            // 8MB: tmph+tmpl, later h fp32
    short* tmph = (short*)tmpRegion;
    short* tmpl = tmph + (size_t)B_ROWS * H_DIM;
    float* hbuf = (float*)tmpRegion;                                // overlay (after ctx2 done)
    float* gateh = (float*)alloc((size_t)B_ROWS * GH_DIM * 4);      // 4MB
    float* gp = (float*)alloc((size_t)B_ROWS * 2 * 4);
    float* ent = (float*)alloc((size_t)B_ROWS * 4);
    float* cxv = (float*)alloc((size_t)B_ROWS * 4);
    float* cyv = (float*)alloc((size_t)B_ROWS * 4);
    float* sqv = (float*)alloc((size_t)B_ROWS * 4);
    float* wgt = (float*)alloc((size_t)B_ROWS * K_NN * 4);
    int* imgi = (int*)alloc((size_t)B_ROWS * 4);
    int* cnt = (int*)alloc(N_IMG * 4);
    int* startb = (int*)alloc(N_IMG * 4);
    int* cursor = (int*)alloc(N_IMG * 4);
    int* perm = (int*)alloc((size_t)B_ROWS * 4);
    int* kidx = (int*)alloc((size_t)B_ROWS * K_NN * 4);
    // weights (persist whole launch): [N][Kpad] hi/lo
    short* wv_h = (short*)alloc(256 * 1024 * 2);
    short* wv_l = (short*)alloc(256 * 1024 * 2);
    short* wt_h = (short*)alloc(256 * 768 * 2);
    short* wt_l = (short*)alloc(256 * 768 * 2);
    short* wx1_h = (short*)alloc(256 * 512 * 2);
    short* wx1_l = (short*)alloc(256 * 512 * 2);
    short* wx2_h = (short*)alloc(256 * 256 * 2);
    short* wx2_l = (short*)alloc(256 * 256 * 2);
    short* wg1_h = (short*)alloc(128 * GIP_DIM * 2);
    short* wg1_l = (short*)alloc(128 * GIP_DIM * 2);
    short* wu1_h = (short*)alloc(512 * 512 * 2);
    short* wu1_l = (short*)alloc(512 * 512 * 2);
    short* wu2_h = (short*)alloc(512 * 512 * 2);
    short* wu2_l = (short*)alloc(512 * 512 * 2);
    short* wc1_h = (short*)alloc(256 * 512 * 2);
    short* wc1_l = (short*)alloc(256 * 512 * 2);
    // overlay region: x-splits first, reused by gi + guh afterwards
    char* R = alloc((size_t)B_ROWS * (DV_DIM + DT_DIM) * 2 * 2);    // 58.7MB
    short* xvh = (short*)R;
    short* xvl = xvh + (size_t)B_ROWS * DV_DIM;
    short* xth = xvl + (size_t)B_ROWS * DV_DIM;
    short* xtl = xth + (size_t)B_ROWS * DT_DIM;
    // after fv/ft: gi (27.2MB) + gu (16MB) overlay into R
    short* gih = (short*)R;
    short* gil = gih + (size_t)B_ROWS * GIP_DIM;
    short* guh = gil + (size_t)B_ROWS * GIP_DIM;
    short* gul = guh + (size_t)B_ROWS * FD_DIM;
    short* fusedh = aggh;  // agg dead after gu1
    short* fusedl = aggl;

    dim3 blk(256);
    dim3 gridRows((B_ROWS + 255) / 256);

    // ---- weight prep (one batched launch) ----
    PrepArgs pa;
    const float* pw[8] = {W_v, W_t, W_ctx1, W_ctx2, W_g1, W_gu1, W_gu2, W_c1};
    short* ph[8] = {wv_h, wt_h, wx1_h, wx2_h, wg1_h, wu1_h, wu2_h, wc1_h};
    short* pl[8] = {wv_l, wt_l, wx1_l, wx2_l, wg1_l, wu1_l, wu2_l, wc1_l};
    int pK[8] = {1024, 768, 512, 256, GI_REAL, 512, 512, 512};
    int pN[8] = {256, 256, 256, 256, 128, 512, 512, 256};
    int pKp[8] = {1024, 768, 512, 256, GIP_DIM, 512, 512, 512};
    int total = 0;
    for (int s = 0; s < 8; ++s) {
        pa.W[s] = pw[s]; pa.h[s] = ph[s]; pa.l[s] = pl[s];
        pa.K[s] = pK[s]; pa.N[s] = pN[s]; pa.Kpad[s] = pKp[s];
        pa.cnt[s] = pN[s] * pKp[s];
        total += pa.cnt[s];
    }
    prep_all_kernel<<<(total + 255) / 256, blk, 0, stream>>>(pa);

    // ---- KNN structure ----
    hipMemsetAsync(cnt, 0, N_IMG * sizeof(int), stream);
    extract_kernel<<<gridRows, blk, 0, stream>>>(x, cxv, cyv, sqv, imgi, cnt);
    scan_kernel<<<1, N_IMG, 0, stream>>>(cnt, startb, cursor);
    scatter_kernel<<<gridRows, blk, 0, stream>>>(imgi, cursor, perm);
    knn_kernel<<<gridRows, blk, 0, stream>>>(cxv, cyv, sqv, imgi, cnt, startb, perm, kidx, wgt);

    // ---- LN + split ----
    ln_split_kernel<<<B_ROWS, blk, 0, stream>>>(x, ln_v_g, ln_v_b, ln_t_g, ln_t_b,
                                                xvh, xvl, xth, xtl);

    // ---- fv / ft -> base fp32 ----
    gemm2_kernel<0><<<128 * 2, blk, 0, stream>>>(xvh, xvl, 1024, wv_h, wv_l, 2,
                                                 base, nullptr, nullptr, FD_DIM, 0, b_v, nullptr, nullptr);
    gemm2_kernel<0><<<128 * 2, blk, 0, stream>>>(xth, xtl, 768, wt_h, wt_l, 2,
                                                 base, nullptr, nullptr, FD_DIM, 256, b_t, nullptr, nullptr);

    // ---- neigh_agg (hi/lo) ----
    gather_kernel<0><<<B_ROWS, blk, 0, stream>>>(base, kidx, wgt, nullptr, aggh, aggl);

    // ---- ctx MLP ----
    gemm2_kernel<3><<<128 * 2, blk, 0, stream>>>(aggh, aggl, 512, wx1_h, wx1_l, 2,
                                                 nullptr, tmph, tmpl, H_DIM, 0, b_ctx1, nullptr, nullptr);
    gemm2_kernel<4><<<128 * 2, blk, 0, stream>>>(tmph, tmpl, 256, wx2_h, wx2_l, 2,
                                                 nullptr, gih, gil, GIP_DIM, FD_DIM + C_CLS, b_ctx2, nullptr, nullptr);

    // ---- class prior + concat into gi ----
    cpcat_kernel<<<B_ROWS, blk, 0, stream>>>(base, W_cp, b_cp, gih, gil);

    // ---- gate ----
    gemm2_kernel<1><<<128 * 1, blk, 0, stream>>>(gih, gil, GIP_DIM, wg1_h, wg1_l, 1,
                                                 gateh, nullptr, nullptr, GH_DIM, 0, b_g1, nullptr, nullptr);
    gate_kernel<<<B_ROWS / 4, blk, 0, stream>>>(gateh, W_g2, b_g2, gp, ent);
    ent_reduce_kernel<<<1, blk, 0, stream>>>(ent, out + (size_t)B_ROWS * C_CLS);

    // ---- spatial update: gather(fused) with inline gate scaling ----
    gather_kernel<1><<<B_ROWS, blk, 0, stream>>>(base, kidx, wgt, gp, aggh, aggl);
    gemm2_kernel<3><<<128 * 4, blk, 0, stream>>>(aggh, aggl, 512, wu1_h, wu1_l, 4,
                                                 nullptr, guh, gul, FD_DIM, 0, b_gu1, nullptr, nullptr);
    gemm2_kernel<5><<<128 * 4, blk, 0, stream>>>(guh, gul, 512, wu2_h, wu2_l, 4,
                                                 nullptr, fusedh, fusedl, FD_DIM, 0, b_gu2, base, gp);

    // ---- classifier head ----
    gemm2_kernel<2><<<128 * 2, blk, 0, stream>>>(fusedh, fusedl, 512, wc1_h, wc1_l, 2,
                                                 hbuf, nullptr, nullptr, H_DIM, 0, b_c1, bn_g, bn_b);
    rowvec_kernel<C_CLS><<<B_ROWS / 4, blk, 0, stream>>>(hbuf, H_DIM, H_DIM, W_c2, b_c2, out, C_CLS);

    (void)in_sizes; (void)n_in; (void)out_size; (void)ws_size;
}

// Round 4
// 242.532 us; speedup vs baseline: 4.2101x; 1.1745x over previous
//
#include <hip/hip_runtime.h>
#include <math.h>

#define B_ROWS 8192
#define DV_DIM 1024
#define DT_DIM 768
#define H_DIM 256
#define C_CLS 5
#define GH_DIM 128
#define K_NN 8
#define FD_DIM 512
#define GIP_DIM 832
#define GI_REAL 773
#define XCOLS 1797
#define NEGV -1000000000.0f
#define LN_EPS_F 1e-5f
#define BN_EPS_F 1e-5f
#define N_IMG 512
#define EW_F 0.01f
#define ALPHA_F 0.5f

typedef __attribute__((ext_vector_type(8))) short short8v;
typedef __attribute__((ext_vector_type(4))) float f32x4;

__device__ inline short bf16r(float f) {
    unsigned u = __float_as_uint(f);
    return (short)((u + 0x7fffu + ((u >> 16) & 1u)) >> 16);
}

__device__ inline void split2(float f, short* h, short* l) {
    unsigned u = __float_as_uint(f);
    unsigned uh = (u + 0x7fffu + ((u >> 16) & 1u)) >> 16;
    float fh = __uint_as_float(uh << 16);
    float fl = f - fh;
    unsigned ul = __float_as_uint(fl);
    *h = (short)uh;
    *l = (short)((ul + 0x7fffu + ((ul >> 16) & 1u)) >> 16);
}

// ---------------- batched weight prep: W[K][N] fp32 -> [N][Kpad] bf16 hi(/lo) ----------------
struct PrepArgs {
    const float* W[8];
    short* h[8];
    short* l[8];
    int K[8];
    int N[8];
    int Kpad[8];
    int cnt[8];
    int needL[8];
};

__global__ void prep_all_kernel(PrepArgs a) {
    int idx = blockIdx.x * blockDim.x + threadIdx.x;
#pragma unroll
    for (int s = 0; s < 8; ++s) {
        if (idx < a.cnt[s]) {
            int Kp = a.Kpad[s];
            int n = idx / Kp, k = idx - n * Kp;
            float f = (k < a.K[s]) ? a.W[s][(size_t)k * a.N[s] + n] : 0.f;
            short hh, ll;
            split2(f, &hh, &ll);
            a.h[s][idx] = hh;
            if (a.needL[s]) a.l[s][idx] = ll;
            return;
        }
        idx -= a.cnt[s];
    }
}

// ---------------- KNN structure ----------------
__global__ void extract_kernel(const float* __restrict__ x,
                               float* __restrict__ cx, float* __restrict__ cy,
                               float* __restrict__ sq, int* __restrict__ imgi,
                               int* __restrict__ cnt) {
    int i = blockIdx.x * blockDim.x + threadIdx.x;
    if (i >= B_ROWS) return;
    const float* row = x + (size_t)i * XCOLS;
    float a = row[DV_DIM + DT_DIM];
    float b = row[DV_DIM + DT_DIM + 1];
    cx[i] = a; cy[i] = b; sq[i] = a * a + b * b;
    int m = (int)row[DV_DIM + DT_DIM + 4];
    imgi[i] = m;
    atomicAdd(&cnt[m], 1);
}

__global__ void scan_kernel(const int* __restrict__ cnt, int* __restrict__ start,
                            int* __restrict__ cursor) {
    __shared__ int s[N_IMG];
    int t = threadIdx.x;
    s[t] = cnt[t];
    __syncthreads();
    for (int off = 1; off < N_IMG; off <<= 1) {
        int v = (t >= off) ? s[t - off] : 0;
        __syncthreads();
        s[t] += v;
        __syncthreads();
    }
    int st = s[t] - cnt[t];
    start[t] = st;
    cursor[t] = st;
}

__global__ void scatter_kernel(const int* __restrict__ imgi, int* __restrict__ cursor,
                               int* __restrict__ perm) {
    int i = blockIdx.x * blockDim.x + threadIdx.x;
    if (i >= B_ROWS) return;
    int pos = atomicAdd(&cursor[imgi[i]], 1);
    perm[pos] = i;
}

__global__ void knn_kernel(const float* __restrict__ cx, const float* __restrict__ cy,
                           const float* __restrict__ sq, const int* __restrict__ imgi,
                           const int* __restrict__ cnt, const int* __restrict__ start,
                           const int* __restrict__ perm, int* __restrict__ knn_idx,
                           float* __restrict__ knn_w) {
    int i = blockIdx.x * blockDim.x + threadIdx.x;
    if (i >= B_ROWS) return;
    float xi = cx[i], yi = cy[i], si = sq[i];
    float vals[K_NN];
    int ids[K_NN];
#pragma unroll
    for (int k = 0; k < K_NN; ++k) { vals[k] = NEGV; ids[k] = i; }
    int m = imgi[i];
    int s = cnt[m];
    if (s >= 2) {
        int st = start[m];
        for (int t = 0; t < s; ++t) {
            int j = perm[st + t];
            if (j == i) continue;
            float d2 = si + sq[j] - 2.f * (xi * cx[j] + yi * cy[j]);
            d2 = fmaxf(d2, 0.f);
            float v = -sqrtf(d2);
            if (v > vals[K_NN - 1]) {
                int p = K_NN - 1;
                while (p > 0 && vals[p - 1] < v) {
                    vals[p] = vals[p - 1]; ids[p] = ids[p - 1]; --p;
                }
                vals[p] = v; ids[p] = j;
            }
        }
    } else {
        for (int j = 0; j < B_ROWS; ++j) {
            if (j == i) continue;
            float d2 = si + sq[j] - 2.f * (xi * cx[j] + yi * cy[j]);
            d2 = fmaxf(d2, 0.f);
            float v = -sqrtf(d2);
            if (v > vals[K_NN - 1]) {
                int p = K_NN - 1;
                while (p > 0 && vals[p - 1] < v) {
                    vals[p] = vals[p - 1]; ids[p] = ids[p - 1]; --p;
                }
                vals[p] = v; ids[p] = j;
            }
        }
    }
    float mx = vals[0];
    float e[K_NN];
    float sum = 0.f;
#pragma unroll
    for (int k = 0; k < K_NN; ++k) { e[k] = expf(vals[k] - mx); sum += e[k]; }
    float inv = 1.f / sum;
#pragma unroll
    for (int k = 0; k < K_NN; ++k) {
        knn_w[(size_t)i * K_NN + k] = e[k] * inv;
        knn_idx[(size_t)i * K_NN + k] = ids[k];
    }
}

// ---------------- fused layernorm + hi/lo split for both segments ----------------
__global__ __launch_bounds__(256) void ln_split_kernel(
    const float* __restrict__ x,
    const float* __restrict__ gv, const float* __restrict__ bv,
    const float* __restrict__ gt, const float* __restrict__ bt,
    short* __restrict__ xvh, short* __restrict__ xvl,
    short* __restrict__ xth, short* __restrict__ xtl) {
    int row = blockIdx.x;
    int t = threadIdx.x;
    const float* xr = x + (size_t)row * XCOLS;
    __shared__ float red[256];

    float v[4];
#pragma unroll
    for (int k = 0; k < 4; ++k) v[k] = xr[t + k * 256];
    float sum = v[0] + v[1] + v[2] + v[3];
    red[t] = sum;
    __syncthreads();
    for (int off = 128; off; off >>= 1) {
        if (t < off) red[t] += red[t + off];
        __syncthreads();
    }
    float mean = red[0] * (1.f / DV_DIM);
    __syncthreads();
    float vs = 0.f;
#pragma unroll
    for (int k = 0; k < 4; ++k) { float d = v[k] - mean; vs += d * d; }
    red[t] = vs;
    __syncthreads();
    for (int off = 128; off; off >>= 1) {
        if (t < off) red[t] += red[t + off];
        __syncthreads();
    }
    float rs = rsqrtf(red[0] * (1.f / DV_DIM) + LN_EPS_F);
#pragma unroll
    for (int k = 0; k < 4; ++k) {
        int j = t + k * 256;
        float y = (v[k] - mean) * rs * gv[j] + bv[j];
        split2(y, &xvh[(size_t)row * DV_DIM + j], &xvl[(size_t)row * DV_DIM + j]);
    }
    __syncthreads();

    float u[3];
#pragma unroll
    for (int k = 0; k < 3; ++k) u[k] = xr[DV_DIM + t + k * 256];
    sum = u[0] + u[1] + u[2];
    red[t] = sum;
    __syncthreads();
    for (int off = 128; off; off >>= 1) {
        if (t < off) red[t] += red[t + off];
        __syncthreads();
    }
    mean = red[0] * (1.f / DT_DIM);
    __syncthreads();
    vs = 0.f;
#pragma unroll
    for (int k = 0; k < 3; ++k) { float d = u[k] - mean; vs += d * d; }
    red[t] = vs;
    __syncthreads();
    for (int off = 128; off; off >>= 1) {
        if (t < off) red[t] += red[t + off];
        __syncthreads();
    }
    rs = rsqrtf(red[0] * (1.f / DT_DIM) + LN_EPS_F);
#pragma unroll
    for (int k = 0; k < 3; ++k) {
        int j = t + k * 256;
        float y = (u[k] - mean) * rs * gt[j] + bt[j];
        split2(y, &xth[(size_t)row * DT_DIM + j], &xtl[(size_t)row * DT_DIM + j]);
    }
}

// ---------------- MFMA GEMM: tile 64 x (32*NF), 4 waves (2x2), BK=64 ----------------
// NPROD=3: split-bf16 (fp32-grade): acc += Ah*Bh + Al*Bh + Ah*Bl
// NPROD=1: plain bf16 single product
// MODE 0: Cf = acc+bias
// MODE 1: Cf = relu(acc+bias)
// MODE 2: Cf = relu((acc+bias)*bnscale + bnb)
// MODE 3: Ch = bf16(relu(acc+bias))
// MODE 4: Ch = bf16(acc+bias)
// MODE 5: Ch/Cl = split(base*gate + 0.5*(acc+bias))
struct GemmPair {
    const short* Ah; const short* Al;
    const short* Bh; const short* Bl;
    const float* bias;
    int K; int ncb; int colOff;
};

template <int MODE, int NPROD, int NF>
__global__ __launch_bounds__(256) void gemm2_kernel(
    GemmPair P0, GemmPair P1, int nblk0,
    float* __restrict__ Cf, short* __restrict__ Ch, short* __restrict__ Cl,
    int ldc, const float* __restrict__ aux1, const float* __restrict__ aux2) {
    constexpr int ASZ = 4096;        // 64 rows x 64 shorts (8KB)
    constexpr int BROWS = 32 * NF;
    constexpr int BSZ = BROWS * 64;
    __shared__ short lds[(NPROD == 3 ? 2 : 1) * (ASZ + BSZ)];
    short* sAh = lds;
    short* sAl = lds + ASZ;                                  // valid only if NPROD==3
    short* sBh = lds + (NPROD == 3 ? 2 * ASZ : ASZ);
    short* sBl = sBh + BSZ;                                  // valid only if NPROD==3

    const int tid = threadIdx.x;
    const int lane = tid & 63;
    const int wave = tid >> 6;
    const int wm = wave >> 1, wn = wave & 1;
    const int l15 = lane & 15, lq = lane >> 4;

    // bijective XCD swizzle (m204)
    int nwg = gridDim.x;
    int wg = blockIdx.x;
    int q = nwg >> 3, r = nwg & 7;
    int xc = wg & 7, ii = wg >> 3;
    int wid = (xc < r ? xc * (q + 1) : r * (q + 1) + (xc - r) * q) + ii;

    GemmPair G = P0;
    if (wid >= nblk0) { G = P1; wid -= nblk0; }

    const int panel = wid / G.ncb, cb = wid - panel * G.ncb;
    const long rowBase = (long)panel * 64;
    const int colBase = cb * (32 * NF);
    const int K = G.K;

    f32x4 acc[2][NF];
#pragma unroll
    for (int i = 0; i < 2; ++i)
#pragma unroll
        for (int j = 0; j < NF; ++j) acc[i][j] = (f32x4){0.f, 0.f, 0.f, 0.f};

    short8v pAh[2], pAl[2], pBh[NF], pBl[NF];

    const int ar0 = tid >> 3, ac = tid & 7;
    const int ar1 = (tid + 256) >> 3;

    // prologue: load tile 0
    {
        long go0 = (rowBase + ar0) * K + ac * 8;
        long go1 = (rowBase + ar1) * K + ac * 8;
        pAh[0] = *(const short8v*)(G.Ah + go0);
        pAh[1] = *(const short8v*)(G.Ah + go1);
        if constexpr (NPROD == 3) {
            pAl[0] = *(const short8v*)(G.Al + go0);
            pAl[1] = *(const short8v*)(G.Al + go1);
        }
#pragma unroll
        for (int j = 0; j < NF; ++j) {
            int cid = tid + 256 * j;
            int cl = cid >> 3, c = cid & 7;
            long go = (colBase + cl) * (long)K + c * 8;
            pBh[j] = *(const short8v*)(G.Bh + go);
            if constexpr (NPROD == 3) pBl[j] = *(const short8v*)(G.Bl + go);
        }
    }

    const int nsteps = K >> 6;
    for (int s = 0; s < nsteps; ++s) {
        __syncthreads();
        {
            int off0 = ar0 * 64 + ((ac ^ (ar0 & 7)) << 3);
            int off1 = ar1 * 64 + ((ac ^ (ar1 & 7)) << 3);
            *(short8v*)(sAh + off0) = pAh[0];
            *(short8v*)(sAh + off1) = pAh[1];
            if constexpr (NPROD == 3) {
                *(short8v*)(sAl + off0) = pAl[0];
                *(short8v*)(sAl + off1) = pAl[1];
            }
#pragma unroll
            for (int j = 0; j < NF; ++j) {
                int cid = tid + 256 * j;
                int cl = cid >> 3, c = cid & 7;
                int off = cl * 64 + ((c ^ (cl & 7)) << 3);
                *(short8v*)(sBh + off) = pBh[j];
                if constexpr (NPROD == 3) *(short8v*)(sBl + off) = pBl[j];
            }
        }
        __syncthreads();
        if (s + 1 < nsteps) {
            long ko = (long)(s + 1) * 64;
            long go0 = (rowBase + ar0) * K + ko + ac * 8;
            long go1 = (rowBase + ar1) * K + ko + ac * 8;
            pAh[0] = *(const short8v*)(G.Ah + go0);
            pAh[1] = *(const short8v*)(G.Ah + go1);
            if constexpr (NPROD == 3) {
                pAl[0] = *(const short8v*)(G.Al + go0);
                pAl[1] = *(const short8v*)(G.Al + go1);
            }
#pragma unroll
            for (int j = 0; j < NF; ++j) {
                int cid = tid + 256 * j;
                int cl = cid >> 3, c = cid & 7;
                long go = (colBase + cl) * (long)K + ko + c * 8;
                pBh[j] = *(const short8v*)(G.Bh + go);
                if constexpr (NPROD == 3) pBl[j] = *(const short8v*)(G.Bl + go);
            }
        }
#pragma unroll
        for (int ksub = 0; ksub < 2; ++ksub) {
            int cc = ksub * 4 + lq;
            short8v afh[2], afl[2], bfh[NF], bfl[NF];
#pragma unroll
            for (int mf = 0; mf < 2; ++mf) {
                int rr = wm * 32 + mf * 16 + l15;
                int off = rr * 64 + ((cc ^ (rr & 7)) << 3);
                afh[mf] = *(short8v*)(sAh + off);
                if constexpr (NPROD == 3) afl[mf] = *(short8v*)(sAl + off);
            }
#pragma unroll
            for (int nf = 0; nf < NF; ++nf) {
                int cl = wn * (NF * 16) + nf * 16 + l15;
                int off = cl * 64 + ((cc ^ (cl & 7)) << 3);
                bfh[nf] = *(short8v*)(sBh + off);
                if constexpr (NPROD == 3) bfl[nf] = *(short8v*)(sBl + off);
            }
#pragma unroll
            for (int mf = 0; mf < 2; ++mf)
#pragma unroll
                for (int nf = 0; nf < NF; ++nf) {
                    acc[mf][nf] = __builtin_amdgcn_mfma_f32_16x16x32_bf16(afh[mf], bfh[nf], acc[mf][nf], 0, 0, 0);
                    if constexpr (NPROD == 3) {
                        acc[mf][nf] = __builtin_amdgcn_mfma_f32_16x16x32_bf16(afl[mf], bfh[nf], acc[mf][nf], 0, 0, 0);
                        acc[mf][nf] = __builtin_amdgcn_mfma_f32_16x16x32_bf16(afh[mf], bfl[nf], acc[mf][nf], 0, 0, 0);
                    }
                }
        }
    }

    // epilogue: C/D layout col = lane&15, row = (lane>>4)*4 + reg
#pragma unroll
    for (int mf = 0; mf < 2; ++mf)
#pragma unroll
        for (int nf = 0; nf < NF; ++nf) {
            int col = colBase + wn * (NF * 16) + nf * 16 + l15;
            long row0 = rowBase + wm * 32 + mf * 16 + lq * 4;
#pragma unroll
            for (int rr = 0; rr < 4; ++rr) {
                long row = row0 + rr;
                float v = acc[mf][nf][rr] + G.bias[col];
                long o = row * ldc + G.colOff + col;
                if (MODE == 0) {
                    Cf[o] = v;
                } else if (MODE == 1) {
                    Cf[o] = fmaxf(v, 0.f);
                } else if (MODE == 2) {
                    v = v * (aux1[col] * rsqrtf(1.f + BN_EPS_F)) + aux2[col];
                    Cf[o] = fmaxf(v, 0.f);
                } else if (MODE == 3) {
                    Ch[o] = bf16r(fmaxf(v, 0.f));
                } else if (MODE == 4) {
                    Ch[o] = bf16r(v);
                } else {  // MODE 5
                    float g = aux2[row * 2 + (col >= H_DIM ? 1 : 0)];
                    float fv = aux1[row * FD_DIM + col] * g + ALPHA_F * v;
                    split2(fv, &Ch[o], &Cl[o]);
                }
            }
        }
}

// ---------------- weighted gather (optionally gate-scaled) -> single bf16 ----------------
template <int GATE>
__global__ __launch_bounds__(256) void gather_kernel(const float* __restrict__ feat,
                                                     const int* __restrict__ knn_idx,
                                                     const float* __restrict__ knn_w,
                                                     const float* __restrict__ gp,
                                                     short* __restrict__ oh) {
    int row = blockIdx.x;
    int t = threadIdx.x;
    int jj[K_NN];
    float ww[K_NN], g0[K_NN], g1[K_NN];
#pragma unroll
    for (int k = 0; k < K_NN; ++k) {
        jj[k] = knn_idx[(size_t)row * K_NN + k];
        ww[k] = knn_w[(size_t)row * K_NN + k];
        if (GATE) {
            g0[k] = gp[(size_t)jj[k] * 2 + 0];
            g1[k] = gp[(size_t)jj[k] * 2 + 1];
        }
    }
#pragma unroll
    for (int half = 0; half < 2; ++half) {
        int d = t + half * 256;
        float s = 0.f;
#pragma unroll
        for (int k = 0; k < K_NN; ++k) {
            float f = feat[(size_t)jj[k] * FD_DIM + d];
            if (GATE) f *= (d < H_DIM) ? g0[k] : g1[k];
            s = fmaf(ww[k], f, s);
        }
        oh[(size_t)row * FD_DIM + d] = bf16r(s);
    }
}

// ---------------- class prior + gi concat (single bf16) ----------------
__global__ __launch_bounds__(256) void cpcat_kernel(const float* __restrict__ base,
                                                    const float* __restrict__ Wcp,
                                                    const float* __restrict__ bcp,
                                                    short* __restrict__ gih) {
    int row = blockIdx.x;
    int t = threadIdx.x;
    float a = base[(size_t)row * FD_DIM + t];
    float b = base[(size_t)row * FD_DIM + t + 256];
    float acc[C_CLS];
#pragma unroll
    for (int n = 0; n < C_CLS; ++n)
        acc[n] = a * Wcp[t * C_CLS + n] + b * Wcp[(t + 256) * C_CLS + n];
    __shared__ float red[256];
    __shared__ float lg[C_CLS];
#pragma unroll
    for (int n = 0; n < C_CLS; ++n) {
        red[t] = acc[n];
        __syncthreads();
        for (int off = 128; off; off >>= 1) {
            if (t < off) red[t] += red[t + off];
            __syncthreads();
        }
        if (t == 0) lg[n] = red[0] + bcp[n];
        __syncthreads();
    }
    size_t go = (size_t)row * GIP_DIM;
    if (t == 0) {
        float mx = lg[0];
#pragma unroll
        for (int n = 1; n < C_CLS; ++n) mx = fmaxf(mx, lg[n]);
        float s = 0.f;
        float e[C_CLS];
#pragma unroll
        for (int n = 0; n < C_CLS; ++n) { e[n] = expf(lg[n] - mx); s += e[n]; }
        float inv = 1.f / s;
#pragma unroll
        for (int n = 0; n < C_CLS; ++n) gih[go + FD_DIM + n] = bf16r(e[n] * inv);
    }
    gih[go + t] = bf16r(a);
    gih[go + t + 256] = bf16r(b);
    if (t < GIP_DIM - GI_REAL) gih[go + GI_REAL + t] = 0;
}

// ---------------- gate head ----------------
__global__ __launch_bounds__(256) void gate_kernel(const float* __restrict__ gh,
                                                   const float* __restrict__ W2,
                                                   const float* __restrict__ b2,
                                                   float* __restrict__ gp,
                                                   float* __restrict__ ent) {
    int wave = threadIdx.x >> 6;
    int lane = threadIdx.x & 63;
    int row = blockIdx.x * 4 + wave;
    if (row >= B_ROWS) return;
    const float* xr = gh + (size_t)row * GH_DIM;
    float a0 = 0.f, a1 = 0.f;
    for (int k = lane; k < GH_DIM; k += 64) {
        float xv = xr[k];
        a0 = fmaf(xv, W2[k * 2 + 0], a0);
        a1 = fmaf(xv, W2[k * 2 + 1], a1);
    }
    for (int off = 32; off; off >>= 1) {
        a0 += __shfl_down(a0, off);
        a1 += __shfl_down(a1, off);
    }
    if (lane == 0) {
        float l0 = a0 + b2[0], l1 = a1 + b2[1];
        float mx = fmaxf(l0, l1);
        float e0 = expf(l0 - mx), e1 = expf(l1 - mx);
        float s = e0 + e1;
        float p0 = e0 / s, p1 = e1 / s;
        gp[(size_t)row * 2 + 0] = p0;
        gp[(size_t)row * 2 + 1] = p1;
        ent[row] = -(p0 * logf(p0 + 1e-8f) + p1 * logf(p1 + 1e-8f));
    }
}

__global__ void ent_reduce_kernel(const float* __restrict__ ent, float* __restrict__ out) {
    __shared__ float red[256];
    float s = 0.f;
    for (int i = threadIdx.x; i < B_ROWS; i += 256) s += ent[i];
    red[threadIdx.x] = s;
    __syncthreads();
    for (int off = 128; off; off >>= 1) {
        if (threadIdx.x < off) red[threadIdx.x] += red[threadIdx.x + off];
        __syncthreads();
    }
    if (threadIdx.x == 0) out[0] = red[0] * (EW_F / (float)B_ROWS);
}

// ---------------- small-N row matvec (final logits) ----------------
template <int NOUT>
__global__ __launch_bounds__(256) void rowvec_kernel(const float* __restrict__ X, int ldx, int K,
                                                     const float* __restrict__ W,
                                                     const float* __restrict__ bias,
                                                     float* __restrict__ Y, int ldy) {
    int wave = threadIdx.x >> 6;
    int lane = threadIdx.x & 63;
    int row = blockIdx.x * 4 + wave;
    if (row >= B_ROWS) return;
    const float* xr = X + (size_t)row * ldx;
    float acc[NOUT];
#pragma unroll
    for (int n = 0; n < NOUT; ++n) acc[n] = 0.f;
    for (int k = lane; k < K; k += 64) {
        float xv = xr[k];
#pragma unroll
        for (int n = 0; n < NOUT; ++n) acc[n] = fmaf(xv, W[(size_t)k * NOUT + n], acc[n]);
    }
#pragma unroll
    for (int n = 0; n < NOUT; ++n)
        for (int off = 32; off; off >>= 1) acc[n] += __shfl_down(acc[n], off);
    if (lane == 0) {
#pragma unroll
        for (int n = 0; n < NOUT; ++n) Y[(size_t)row * ldy + n] = acc[n] + bias[n];
    }
}

extern "C" void kernel_launch(void* const* d_in, const int* in_sizes, int n_in,
                              void* d_out, int out_size, void* d_ws, size_t ws_size,
                              hipStream_t stream) {
    const float* x = (const float*)d_in[0];
    const float* ln_v_g = (const float*)d_in[1];
    const float* ln_v_b = (const float*)d_in[2];
    const float* ln_t_g = (const float*)d_in[3];
    const float* ln_t_b = (const float*)d_in[4];
    const float* W_v = (const float*)d_in[5];
    const float* b_v = (const float*)d_in[6];
    const float* W_t = (const float*)d_in[7];
    const float* b_t = (const float*)d_in[8];
    const float* W_cp = (const float*)d_in[9];
    const float* b_cp = (const float*)d_in[10];
    const float* W_ctx1 = (const float*)d_in[11];
    const float* b_ctx1 = (const float*)d_in[12];
    const float* W_ctx2 = (const float*)d_in[13];
    const float* b_ctx2 = (const float*)d_in[14];
    const float* W_g1 = (const float*)d_in[15];
    const float* b_g1 = (const float*)d_in[16];
    const float* W_g2 = (const float*)d_in[17];
    const float* b_g2 = (const float*)d_in[18];
    const float* W_gu1 = (const float*)d_in[19];
    const float* b_gu1 = (const float*)d_in[20];
    const float* W_gu2 = (const float*)d_in[21];
    const float* b_gu2 = (const float*)d_in[22];
    const float* W_c1 = (const float*)d_in[23];
    const float* b_c1 = (const float*)d_in[24];
    const float* bn_g = (const float*)d_in[25];
    const float* bn_b = (const float*)d_in[26];
    const float* W_c2 = (const float*)d_in[27];
    const float* b_c2 = (const float*)d_in[28];

    float* out = (float*)d_out;

    // ---- workspace arena ----
    char* wsb = (char*)d_ws;
    size_t off = 0;
    auto alloc = [&](size_t bytes) {
        char* p = wsb + off;
        off += (bytes + 255) & ~(size_t)255;
        return p;
    };
    float* base = (float*)alloc((size_t)B_ROWS * FD_DIM * 4);       // persists
    short* aggh = (short*)alloc((size_t)B_ROWS * FD_DIM * 2);       // agg, later fused_h
    short* aggl = (short*)alloc((size_t)B_ROWS * FD_DIM * 2);       // fused_l
    char* tmpRegion = alloc((size_t)B_ROWS * H_DIM * 4);            // tmph, later hbuf
    short* tmph = (short*)tmpRegion;
    float* hbuf = (float*)tmpRegion;
    float* gateh = (float*)alloc((size_t)B_ROWS * GH_DIM * 4);
    float* gp = (float*)alloc((size_t)B_ROWS * 2 * 4);
    float* ent = (float*)alloc((size_t)B_ROWS * 4);
    float* cxv = (float*)alloc((size_t)B_ROWS * 4);
    float* cyv = (float*)alloc((size_t)B_ROWS * 4);
    float* sqv = (float*)alloc((size_t)B_ROWS * 4);
    float* wgt = (float*)alloc((size_t)B_ROWS * K_NN * 4);
    int* imgi = (int*)alloc((size_t)B_ROWS * 4);
    int* cnt = (int*)alloc(N_IMG * 4);
    int* startb = (int*)alloc(N_IMG * 4);
    int* cursor = (int*)alloc(N_IMG * 4);
    int* perm = (int*)alloc((size_t)B_ROWS * 4);
    int* kidx = (int*)alloc((size_t)B_ROWS * K_NN * 4);
    short* wv_h = (short*)alloc(256 * 1024 * 2);
    short* wv_l = (short*)alloc(256 * 1024 * 2);
    short* wt_h = (short*)alloc(256 * 768 * 2);
    short* wt_l = (short*)alloc(256 * 768 * 2);
    short* wx1_h = (short*)alloc(256 * 512 * 2);
    short* wx2_h = (short*)alloc(256 * 256 * 2);
    short* wg1_h = (short*)alloc(128 * GIP_DIM * 2);
    short* wu1_h = (short*)alloc(512 * 512 * 2);
    short* wu2_h = (short*)alloc(512 * 512 * 2);
    short* wc1_h = (short*)alloc(256 * 512 * 2);
    short* wc1_l = (short*)alloc(256 * 512 * 2);
    short* wdump = (short*)alloc(512 * 512 * 2);   // scratch l for single weights
    // overlay region: x-splits, then gi + guh
    char* R = alloc((size_t)B_ROWS * (DV_DIM + DT_DIM) * 2 * 2);
    short* xvh = (short*)R;
    short* xvl = xvh + (size_t)B_ROWS * DV_DIM;
    short* xth = xvl + (size_t)B_ROWS * DV_DIM;
    short* xtl = xth + (size_t)B_ROWS * DT_DIM;
    short* gih = (short*)R;
    short* guh = gih + (size_t)B_ROWS * GIP_DIM;
    short* fusedh = aggh;
    short* fusedl = aggl;

    dim3 blk(256);
    dim3 gridRows((B_ROWS + 255) / 256);

    // ---- weight prep ----
    PrepArgs pa;
    const float* pw[8] = {W_v, W_t, W_ctx1, W_ctx2, W_g1, W_gu1, W_gu2, W_c1};
    short* ph[8] = {wv_h, wt_h, wx1_h, wx2_h, wg1_h, wu1_h, wu2_h, wc1_h};
    short* pl[8] = {wv_l, wt_l, wdump, wdump, wdump, wdump, wdump, wc1_l};
    int pK[8] = {1024, 768, 512, 256, GI_REAL, 512, 512, 512};
    int pN[8] = {256, 256, 256, 256, 128, 512, 512, 256};
    int pKp[8] = {1024, 768, 512, 256, GIP_DIM, 512, 512, 512};
    int pL[8] = {1, 1, 0, 0, 0, 0, 0, 1};
    int total = 0;
    for (int s = 0; s < 8; ++s) {
        pa.W[s] = pw[s]; pa.h[s] = ph[s]; pa.l[s] = pl[s];
        pa.K[s] = pK[s]; pa.N[s] = pN[s]; pa.Kpad[s] = pKp[s];
        pa.cnt[s] = pN[s] * pKp[s];
        pa.needL[s] = pL[s];
        total += pa.cnt[s];
    }
    prep_all_kernel<<<(total + 255) / 256, blk, 0, stream>>>(pa);

    // ---- KNN structure ----
    hipMemsetAsync(cnt, 0, N_IMG * sizeof(int), stream);
    extract_kernel<<<gridRows, blk, 0, stream>>>(x, cxv, cyv, sqv, imgi, cnt);
    scan_kernel<<<1, N_IMG, 0, stream>>>(cnt, startb, cursor);
    scatter_kernel<<<gridRows, blk, 0, stream>>>(imgi, cursor, perm);
    knn_kernel<<<gridRows, blk, 0, stream>>>(cxv, cyv, sqv, imgi, cnt, startb, perm, kidx, wgt);

    // ---- LN + split ----
    ln_split_kernel<<<B_ROWS, blk, 0, stream>>>(x, ln_v_g, ln_v_b, ln_t_g, ln_t_b,
                                                xvh, xvl, xth, xtl);

    // ---- fv + ft fused dual dispatch (split-3, NF=4) -> base ----
    GemmPair fvP{xvh, xvl, wv_h, wv_l, b_v, 1024, 2, 0};
    GemmPair ftP{xth, xtl, wt_h, wt_l, b_t, 768, 2, 256};
    gemm2_kernel<0, 3, 4><<<512, blk, 0, stream>>>(fvP, ftP, 256, base, nullptr, nullptr,
                                                   FD_DIM, nullptr, nullptr);

    // ---- neigh_agg (bf16) ----
    gather_kernel<0><<<B_ROWS, blk, 0, stream>>>(base, kidx, wgt, nullptr, aggh);

    // ---- ctx MLP (single-product) ----
    GemmPair x1P{aggh, nullptr, wx1_h, nullptr, b_ctx1, 512, 4, 0};
    gemm2_kernel<3, 1, 2><<<512, blk, 0, stream>>>(x1P, x1P, 512, nullptr, tmph, nullptr,
                                                   H_DIM, nullptr, nullptr);
    GemmPair x2P{tmph, nullptr, wx2_h, nullptr, b_ctx2, 256, 4, FD_DIM + C_CLS};
    gemm2_kernel<4, 1, 2><<<512, blk, 0, stream>>>(x2P, x2P, 512, nullptr, gih, nullptr,
                                                   GIP_DIM, nullptr, nullptr);

    // ---- class prior + concat into gi ----
    cpcat_kernel<<<B_ROWS, blk, 0, stream>>>(base, W_cp, b_cp, gih);

    // ---- gate (single-product) ----
    GemmPair g1P{gih, nullptr, wg1_h, nullptr, b_g1, GIP_DIM, 2, 0};
    gemm2_kernel<1, 1, 2><<<256, blk, 0, stream>>>(g1P, g1P, 256, gateh, nullptr, nullptr,
                                                   GH_DIM, nullptr, nullptr);
    gate_kernel<<<B_ROWS / 4, blk, 0, stream>>>(gateh, W_g2, b_g2, gp, ent);
    ent_reduce_kernel<<<1, blk, 0, stream>>>(ent, out + (size_t)B_ROWS * C_CLS);

    // ---- spatial update (single-product) ----
    gather_kernel<1><<<B_ROWS, blk, 0, stream>>>(base, kidx, wgt, gp, aggh);
    GemmPair u1P{aggh, nullptr, wu1_h, nullptr, b_gu1, 512, 4, 0};
    gemm2_kernel<3, 1, 4><<<512, blk, 0, stream>>>(u1P, u1P, 512, nullptr, guh, nullptr,
                                                   FD_DIM, nullptr, nullptr);
    GemmPair u2P{guh, nullptr, wu2_h, nullptr, b_gu2, 512, 4, 0};
    gemm2_kernel<5, 1, 4><<<512, blk, 0, stream>>>(u2P, u2P, 512, nullptr, fusedh, fusedl,
                                                   FD_DIM, base, gp);

    // ---- classifier head (split-3, NF=2) ----
    GemmPair c1P{fusedh, fusedl, wc1_h, wc1_l, b_c1, 512, 4, 0};
    gemm2_kernel<2, 3, 2><<<512, blk, 0, stream>>>(c1P, c1P, 512, hbuf, nullptr, nullptr,
                                                   H_DIM, bn_g, bn_b);
    rowvec_kernel<C_CLS><<<B_ROWS / 4, blk, 0, stream>>>(hbuf, H_DIM, H_DIM, W_c2, b_c2, out, C_CLS);

    (void)in_sizes; (void)n_in; (void)out_size; (void)ws_size;
}